// Round 4
// baseline (1247.759 us; speedup 1.0000x reference)
//
#include <hip/hip_runtime.h>
#include <stdint.h>

// PreEncodedGCN on MI355X — round 4.
// Dtype-agnostic: device-side detector decides whether float inputs are fp32
// or bf16; all input readers branch (wave-uniformly) on the flag; output is
// written in the matching dtype. Internals are bf16 with fp32 accumulation.

typedef unsigned short u16;
typedef __attribute__((ext_vector_type(4))) float f32x4;
typedef __attribute__((ext_vector_type(8))) short short8;

__device__ __forceinline__ float b2f(u16 u){
  union { uint32_t i; float f; } v; v.i = ((uint32_t)u) << 16; return v.f;
}
__device__ __forceinline__ u16 f2b(float f){
  union { float f; uint32_t i; } v; v.f = f;
  uint32_t u = v.i;
  return (u16)((u + 0x7FFFu + ((u >> 16) & 1u)) >> 16);
}
__device__ __forceinline__ u16 rdw(const void* p, size_t i, int f32){
  return f32 ? f2b(((const float*)p)[i]) : ((const u16*)p)[i];
}

// ---------------- dtype detector: 1 = fp32, 0 = bf16 ------------------------
// Even u16 indices of an fp32 array are mantissa words (random exponent field,
// ~16% plausible); of a bf16 array they are real values (~100% plausible).
__global__ void detect_dtype(const u16* enc16, int* flag){
  __shared__ int cnt;
  if (threadIdx.x == 0) cnt = 0;
  __syncthreads();
  unsigned u = enc16[threadIdx.x * 2];
  int e = (u >> 7) & 0xFF;
  if (e >= 100 && e <= 140) atomicAdd(&cnt, 1);
  __syncthreads();
  if (threadIdx.x == 0) flag[0] = (cnt < 128) ? 1 : 0;
}

// ---------------- generic convert-to-bf16 -----------------------------------
__global__ void cvt(const void* __restrict__ in, u16* __restrict__ out, int n,
                    const int* __restrict__ flag){
  int i = blockIdx.x * blockDim.x + threadIdx.x;
  if (i >= n) return;
  out[i] = rdw(in, i, *flag);
}

// ---------------- weight packing: transpose B matrices to [NOUT, K] ----------
__global__ void pack_weights(const void* __restrict__ bases1, const void* __restrict__ root1,
                             const void* __restrict__ w2_rel, const void* __restrict__ w2_root,
                             const void* __restrict__ bases3, const void* __restrict__ root3,
                             const void* __restrict__ w4_rel, const void* __restrict__ w4_root,
                             const void* __restrict__ wd1,
                             u16* __restrict__ B1t, u16* __restrict__ B3t,
                             u16* __restrict__ B2t, u16* __restrict__ B4t,
                             u16* __restrict__ D1t, const int* __restrict__ flag)
{
  int f = *flag;
  int idx = blockIdx.x * blockDim.x + threadIdx.x;
  if (idx < 256*2304) { int o = idx / 2304, k = idx % 2304;
    B1t[idx] = (k < 2048) ? rdw(bases1, k*256 + o, f) : rdw(root1, (k-2048)*256 + o, f); return; }
  idx -= 256*2304;
  if (idx < 256*2304) { int o = idx / 2304, k = idx % 2304;
    B3t[idx] = (k < 2048) ? rdw(bases3, k*256 + o, f) : rdw(root3, (k-2048)*256 + o, f); return; }
  idx -= 256*2304;
  if (idx < 256*512) { int o = idx / 512, k = idx % 512;
    B2t[idx] = (k < 256) ? rdw(w2_rel, k*256 + o, f) : rdw(w2_root, (k-256)*256 + o, f); return; }
  idx -= 256*512;
  if (idx < 256*512) { int o = idx / 512, k = idx % 512;
    B4t[idx] = (k < 256) ? rdw(w4_rel, k*256 + o, f) : rdw(w4_root, (k-256)*256 + o, f); return; }
  idx -= 256*512;
  if (idx < 128*768) { int o = idx / 768, k = idx % 768;
    D1t[idx] = rdw(wd1, k*128 + o, f); }
}

// ---------------- x = encoding + spk_table[speaker] -------------------------
__global__ void build_x(const void* __restrict__ enc, const int* __restrict__ speaker,
                        const u16* __restrict__ spkA /* bf16 [4,256] */,
                        u16* __restrict__ X /* [N,256] */, int N,
                        const int* __restrict__ flag)
{
  int f = *flag;
  int idx = blockIdx.x * blockDim.x + threadIdx.x;
  if (idx >= N * 64) return;
  int n = idx >> 6, c = (idx & 63) * 4;
  int sp = speaker[n];
  ushort4 sv = *(const ushort4*)(spkA + (size_t)sp*256 + c);
  float e0, e1, e2, e3;
  if (f) {
    float4 ev = *(const float4*)((const float*)enc + (size_t)n*256 + c);
    e0 = ev.x; e1 = ev.y; e2 = ev.z; e3 = ev.w;
  } else {
    ushort4 ev = *(const ushort4*)((const u16*)enc + (size_t)n*256 + c);
    e0 = b2f(ev.x); e1 = b2f(ev.y); e2 = b2f(ev.z); e3 = b2f(ev.w);
  }
  ushort4 xv;
  xv.x = f2b(e0 + b2f(sv.x));
  xv.y = f2b(e1 + b2f(sv.y));
  xv.z = f2b(e2 + b2f(sv.z));
  xv.w = f2b(e3 + b2f(sv.w));
  *(ushort4*)(X + (size_t)n*256 + c) = xv;
}

// ---------------- edge histogram (dst degree + per-(dst,rel) counts) ---------
__global__ void edge_hist(const int* __restrict__ ei, const int* __restrict__ et,
                          const int* __restrict__ est,
                          int* cnt_dst, int* cnt1, int* cnt3, int E)
{
  int e = blockIdx.x * blockDim.x + threadIdx.x;
  if (e >= E) return;
  int d = ei[E + e];
  atomicAdd(&cnt_dst[d], 1);
  atomicAdd(&cnt1[d*16 + et[e]], 1);
  atomicAdd(&cnt3[d*16 + est[e]], 1);
}

// ---------------- exclusive prefix over dst degrees (single block) -----------
__global__ void scan_base(const int* __restrict__ cnt_dst, int* __restrict__ basep, int N)
{
  __shared__ int sums[1024];
  int t = threadIdx.x;
  int chunk = (N + 1023) / 1024;
  int lo = t * chunk, hi = lo + chunk; if (hi > N) hi = N; if (lo > N) lo = N;
  int s = 0;
  for (int i = lo; i < hi; i++) s += cnt_dst[i];
  sums[t] = s; __syncthreads();
  for (int off = 1; off < 1024; off <<= 1) {
    int v = (t >= off) ? sums[t - off] : 0;
    __syncthreads();
    sums[t] += v;
    __syncthreads();
  }
  int prefix = (t == 0) ? 0 : sums[t - 1];
  for (int i = lo; i < hi; i++) { basep[i] = prefix; prefix += cnt_dst[i]; }
  if (t == 1023) basep[N] = sums[1023];
}

// ---------------- scatter edges into dst-sorted order, packed ---------------
__global__ void edge_scatter(const int* __restrict__ ei, const int* __restrict__ et,
                             const int* __restrict__ est, const int* __restrict__ basep,
                             int* cursor, int* __restrict__ esorted, int E)
{
  int e = blockIdx.x * blockDim.x + threadIdx.x;
  if (e >= E) return;
  int d = ei[E + e];
  int pos = basep[d] + atomicAdd(&cursor[d], 1);
  esorted[pos] = ei[e] | (et[e] << 17) | (est[e] << 21);  // src<2^17, 4+4 bits rels
}

// ---------------- counts -> 1/max(cnt,1) in-place (int -> float) ------------
__global__ void invert_counts(int* a, int* b, int total)
{
  int i = blockIdx.x * blockDim.x + threadIdx.x;
  if (i >= total) return;
  int c = a[i]; ((float*)a)[i] = 1.0f / (float)(c > 1 ? c : 1);
  int d = b[i]; ((float*)b)[i] = 1.0f / (float)(d > 1 ? d : 1);
}

// ---------------- RGCN aggregation into basis space: wave per node ----------
__global__ __launch_bounds__(256) void rgcn_agg(
    const int* __restrict__ esorted, const int* __restrict__ basep,
    const u16* __restrict__ X /* [N,256] */,
    const u16* __restrict__ comp /* bf16 [16,8] */,
    const float* __restrict__ inv /* [N,16] */,
    u16* __restrict__ Mix /* [CR,2048] */,
    int shift, int n0, int CR)
{
  __shared__ float scomp[128];
  if (threadIdx.x < 128) scomp[threadIdx.x] = b2f(comp[threadIdx.x]);
  __syncthreads();
  int nl = blockIdx.x * 4 + (threadIdx.x >> 6);
  if (nl >= CR) return;
  int n = n0 + nl;
  int lane = threadIdx.x & 63;
  float acc[8][4] = {};
  int e0 = basep[n], e1 = basep[n + 1];
  for (int e = e0; e < e1; e++) {
    int rec = esorted[e];
    int src = rec & 0x1FFFF;
    int r = (rec >> shift) & 15;
    float iv = inv[n * 16 + r];
    ushort4 xr = *(const ushort4*)(X + (size_t)src * 256 + lane * 4);
    float x0 = b2f(xr.x), x1 = b2f(xr.y), x2 = b2f(xr.z), x3 = b2f(xr.w);
    const float* cp = scomp + r * 8;
    #pragma unroll
    for (int b = 0; b < 8; b++) {
      float w = cp[b] * iv;
      acc[b][0] += w * x0; acc[b][1] += w * x1;
      acc[b][2] += w * x2; acc[b][3] += w * x3;
    }
  }
  #pragma unroll
  for (int b = 0; b < 8; b++) {
    ushort4 o;
    o.x = f2b(acc[b][0]); o.y = f2b(acc[b][1]);
    o.z = f2b(acc[b][2]); o.w = f2b(acc[b][3]);
    *(ushort4*)(Mix + (size_t)nl * 2048 + b * 256 + lane * 4) = o;
  }
}

// ---------------- GraphConv sum-aggregation: wave per node ------------------
__global__ __launch_bounds__(256) void gconv_agg(
    const int* __restrict__ esorted, const int* __restrict__ basep,
    const u16* __restrict__ Hin /* [N,256] */,
    u16* __restrict__ Agg /* [N,256] */, int N)
{
  int n = blockIdx.x * 4 + (threadIdx.x >> 6);
  if (n >= N) return;
  int lane = threadIdx.x & 63;
  float a0 = 0, a1 = 0, a2 = 0, a3 = 0;
  int e0 = basep[n], e1 = basep[n + 1];
  for (int e = e0; e < e1; e++) {
    int src = esorted[e] & 0x1FFFF;
    ushort4 h = *(const ushort4*)(Hin + (size_t)src * 256 + lane * 4);
    a0 += b2f(h.x); a1 += b2f(h.y); a2 += b2f(h.z); a3 += b2f(h.w);
  }
  ushort4 o; o.x = f2b(a0); o.y = f2b(a1); o.z = f2b(a2); o.w = f2b(a3);
  *(ushort4*)(Agg + (size_t)n * 256 + lane * 4) = o;
}

// ------------- multi-source bf16 MFMA GEMM: C = [A0|A1|A2] @ Bt^T + bias ----
__global__ __launch_bounds__(256) void gemm_ms(
    const u16* __restrict__ A0, int lda0,
    const u16* __restrict__ A1, int lda1,
    const u16* __restrict__ A2, int lda2,
    int c1, int c2,
    const u16* __restrict__ Bt, /* [NOUT, K] */
    const u16* __restrict__ bias,
    u16* __restrict__ Cout, int ldc,
    int M, int K, int relu)
{
  constexpr int BK = 64;
  constexpr int LDR = 72;                 // padded row stride (u16)
  __shared__ u16 As[128 * LDR];
  __shared__ u16 Bs[128 * LDR];
  int tid = threadIdx.x;
  int wid = tid >> 6, lane = tid & 63;
  int bm = blockIdx.x * 128;
  int bn = blockIdx.y * 128;
  int wm = (wid & 1) * 64, wn = (wid >> 1) * 64;
  f32x4 acc[4][4];
  #pragma unroll
  for (int i = 0; i < 4; i++)
    #pragma unroll
    for (int j = 0; j < 4; j++) acc[i][j] = (f32x4)0.0f;

  int sr = tid >> 3;            // 0..31 staging row within 32-row group
  int sc = (tid & 7) * 8;       // 0..56 staging col (u16)
  int lm = lane & 15, quad = lane >> 4;

  for (int k0 = 0; k0 < K; k0 += BK) {
    const u16* srcp; int ldas, kO;   // wave-uniform (k0 uniform)
    if (k0 < c1)      { srcp = A0; ldas = lda0; kO = k0; }
    else if (k0 < c2) { srcp = A1; ldas = lda1; kO = k0 - c1; }
    else              { srcp = A2; ldas = lda2; kO = k0 - c2; }
    short8 va[4], vb[4];
    #pragma unroll
    for (int g = 0; g < 4; g++) {
      int gr = bm + g * 32 + sr; gr = gr < M ? gr : M - 1;
      va[g] = *(const short8*)(srcp + (size_t)gr * ldas + kO + sc);
      int br = bn + g * 32 + sr;
      vb[g] = *(const short8*)(Bt + (size_t)br * K + k0 + sc);
    }
    #pragma unroll
    for (int g = 0; g < 4; g++) {
      *(short8*)(As + (g * 32 + sr) * LDR + sc) = va[g];
      *(short8*)(Bs + (g * 32 + sr) * LDR + sc) = vb[g];
    }
    __syncthreads();
    #pragma unroll
    for (int kk = 0; kk < BK; kk += 32) {
      short8 af[4], bfv[4];
      #pragma unroll
      for (int mi = 0; mi < 4; mi++) {
        int m = wm + mi * 16 + lm;
        af[mi] = *(const short8*)(As + m * LDR + kk + quad * 8);
      }
      #pragma unroll
      for (int ni = 0; ni < 4; ni++) {
        int nn = wn + ni * 16 + lm;
        bfv[ni] = *(const short8*)(Bs + nn * LDR + kk + quad * 8);
      }
      #pragma unroll
      for (int mi = 0; mi < 4; mi++)
        #pragma unroll
        for (int ni = 0; ni < 4; ni++)
          acc[mi][ni] = __builtin_amdgcn_mfma_f32_16x16x32_bf16(
              af[mi], bfv[ni], acc[mi][ni], 0, 0, 0);
    }
    __syncthreads();
  }
  #pragma unroll
  for (int ni = 0; ni < 4; ni++) {
    int gn = bn + wn + ni * 16 + lm;
    float bv = b2f(bias[gn]);
    #pragma unroll
    for (int mi = 0; mi < 4; mi++) {
      int rbase = bm + wm + mi * 16 + quad * 4;
      #pragma unroll
      for (int r = 0; r < 4; r++) {
        int gm = rbase + r;
        if (gm < M) {
          float v = acc[mi][ni][r] + bv;
          if (relu) v = fmaxf(v, 0.f);
          Cout[(size_t)gm * ldc + gn] = f2b(v);
        }
      }
    }
  }
}

// ---------------- fused MLP tail: 128 -> relu 64 -> 1, wave per node --------
__global__ __launch_bounds__(256) void mlp_tail(
    const u16* __restrict__ h1m, const u16* __restrict__ wd2,
    const u16* __restrict__ bd2, const u16* __restrict__ wd3,
    const u16* __restrict__ bd3, void* __restrict__ outp, int N,
    const int* __restrict__ flag)
{
  int n = blockIdx.x * 4 + (threadIdx.x >> 6);
  if (n >= N) return;
  int lane = threadIdx.x & 63;
  float acc = b2f(bd2[lane]);
  const u16* hr = h1m + (size_t)n * 128;
  #pragma unroll 8
  for (int k = 0; k < 128; k++)
    acc += b2f(hr[k]) * b2f(wd2[k * 64 + lane]);
  float r = fmaxf(acc, 0.f) * b2f(wd3[lane]);
  #pragma unroll
  for (int off = 32; off > 0; off >>= 1) r += __shfl_xor(r, off, 64);
  if (lane == 0) {
    float v = r + b2f(bd3[0]);
    if (*flag) ((float*)outp)[n] = v;
    else       ((u16*)outp)[n] = f2b(v);
  }
}

// ---------------- zero-detection probe (writes only on all-zero buffers) ----
// X->9000@0, Mix->8000@1, hA->7000@2, h1m->6000@3, hB->5000@4
__global__ void probe_zero(const u16* __restrict__ X, const u16* __restrict__ Mix,
                           const u16* __restrict__ hA, const u16* __restrict__ hB,
                           const u16* __restrict__ h1m,
                           void* __restrict__ outp, const int* __restrict__ flag)
{
  __shared__ int nz[5];
  int t = threadIdx.x;
  if (t < 5) nz[t] = 0;
  __syncthreads();
  int a = 0, b = 0, c = 0, d = 0, e = 0;
  for (int i = t; i < 4096; i += 256) {
    a |= X[i]; b |= Mix[i]; c |= hA[i]; d |= hB[i]; e |= h1m[i];
  }
  if (a) atomicOr(&nz[0], 1);
  if (b) atomicOr(&nz[1], 1);
  if (c) atomicOr(&nz[2], 1);
  if (d) atomicOr(&nz[3], 1);
  if (e) atomicOr(&nz[4], 1);
  __syncthreads();
  if (t == 0) {
    int f = *flag;
    auto wr = [&](int idx, float val){
      if (f) ((float*)outp)[idx] = val; else ((u16*)outp)[idx] = f2b(val);
    };
    if (!nz[0]) wr(0, 9000.f);
    if (!nz[1]) wr(1, 8000.f);
    if (!nz[2]) wr(2, 7000.f);
    if (!nz[4]) wr(3, 6000.f);
    if (!nz[3]) wr(4, 5000.f);
  }
}

// informative sentinel: 2000 + ws_size in MB (bf16 write; decodable either way)
__global__ void sentinel(u16* out, int n, float code){
  int i = blockIdx.x * blockDim.x + threadIdx.x;
  if (i < n) out[i] = f2b(code);
}

extern "C" void kernel_launch(void* const* d_in, const int* in_sizes, int n_in,
                              void* d_out, int out_size, void* d_ws, size_t ws_size,
                              hipStream_t stream)
{
  const void* enc     = d_in[0];
  const int* speaker  = (const int*)d_in[1];
  const int* ei       = (const int*)d_in[2];
  const int* et       = (const int*)d_in[3];
  const int* est      = (const int*)d_in[4];
  const void* spk_tab = d_in[5];
  const void* comp1   = d_in[6];
  const void* bases1  = d_in[7];
  const void* root1   = d_in[8];
  const void* b1      = d_in[9];
  const void* w2_rel  = d_in[10];
  const void* b2      = d_in[11];
  const void* w2_root = d_in[12];
  const void* comp3   = d_in[13];
  const void* bases3  = d_in[14];
  const void* root3   = d_in[15];
  const void* b3      = d_in[16];
  const void* w4_rel  = d_in[17];
  const void* b4      = d_in[18];
  const void* w4_root = d_in[19];
  const void* wd1     = d_in[20];
  const void* bd1     = d_in[21];
  const void* wd2     = d_in[22];
  const void* bd2     = d_in[23];
  const void* wd3     = d_in[24];
  const void* bd3     = d_in[25];

  int N = in_sizes[1];     // 60000
  int E = in_sizes[3];     // 480000

  char* ws = (char*)d_ws;
  size_t off = 0;
  auto alloc = [&](size_t bytes) -> char* {
    char* p = ws + off; off = (off + bytes + 255) & ~(size_t)255; return p;
  };
  u16* X    = (u16*)alloc((size_t)N * 256 * 2);   // x = enc+spk; later re-used as bf16 enc
  u16* hA   = (u16*)alloc((size_t)N * 256 * 2);   // RGCN outputs (reused conv1/conv3)
  u16* hB   = (u16*)alloc((size_t)N * 256 * 2);   // h1 final
  u16* hC   = (u16*)alloc((size_t)N * 256 * 2);   // h2 final
  u16* AggB = (u16*)alloc((size_t)N * 256 * 2);   // gconv agg; later aliased by h1m
  u16* h1m  = AggB;                                // [N,128] — AggB dead by then
  u16* B1t  = (u16*)alloc((size_t)256 * 2304 * 2);
  u16* B3t  = (u16*)alloc((size_t)256 * 2304 * 2);
  u16* B2t  = (u16*)alloc((size_t)256 * 512 * 2);
  u16* B4t  = (u16*)alloc((size_t)256 * 512 * 2);
  u16* D1t  = (u16*)alloc((size_t)128 * 768 * 2);
  u16* arena = (u16*)alloc((size_t)11264 * 2);    // small converted weights
  int* flag    = (int*)alloc(256);
  int* inv1    = (int*)alloc((size_t)N * 16 * 4);
  int* inv3    = (int*)alloc((size_t)N * 16 * 4);
  int* cnt_dst = (int*)alloc((size_t)N * 4);
  int* cursor  = (int*)alloc((size_t)N * 4);
  int* basep   = (int*)alloc((size_t)(N + 1) * 4);
  int* esorted = (int*)alloc((size_t)E * 4);

  // arena layout (u16 offsets)
  u16* spkA   = arena + 0;      // 1024
  u16* comp1A = arena + 1024;   // 128
  u16* comp3A = arena + 1152;   // 128
  u16* b1A    = arena + 1280;   // 256
  u16* b2A    = arena + 1536;   // 256
  u16* b3A    = arena + 1792;   // 256
  u16* b4A    = arena + 2048;   // 256
  u16* bd1A   = arena + 2304;   // 128
  u16* wd2A   = arena + 2432;   // 8192
  u16* bd2A   = arena + 10624;  // 64
  u16* wd3A   = arena + 10688;  // 64
  u16* bd3A   = arena + 10752;  // 1

  size_t rem = (ws_size > off) ? (ws_size - off) : 0;
  long crl = (long)(rem / (2048 * 2));
  int chunk_rows = (int)((crl / 128) * 128);
  int Mpad = ((N + 127) / 128) * 128;
  if (chunk_rows > Mpad) chunk_rows = Mpad;

  if (chunk_rows < 128) {
    float code = 2000.0f + (float)(ws_size >> 20);
    sentinel<<<(out_size + 255) / 256, 256, 0, stream>>>((u16*)d_out, out_size, code);
    return;
  }
  u16* Mixblk = (u16*)(ws + off);

  hipMemsetAsync(inv1, 0, (size_t)N * 16 * 4, stream);
  hipMemsetAsync(inv3, 0, (size_t)N * 16 * 4, stream);
  hipMemsetAsync(cnt_dst, 0, (size_t)N * 4, stream);
  hipMemsetAsync(cursor, 0, (size_t)N * 4, stream);

  detect_dtype<<<1, 256, 0, stream>>>((const u16*)enc, flag);

  // small weight conversions
  cvt<<<4, 256, 0, stream>>>(spk_tab, spkA, 1024, flag);
  cvt<<<1, 256, 0, stream>>>(comp1, comp1A, 128, flag);
  cvt<<<1, 256, 0, stream>>>(comp3, comp3A, 128, flag);
  cvt<<<1, 256, 0, stream>>>(b1, b1A, 256, flag);
  cvt<<<1, 256, 0, stream>>>(b2, b2A, 256, flag);
  cvt<<<1, 256, 0, stream>>>(b3, b3A, 256, flag);
  cvt<<<1, 256, 0, stream>>>(b4, b4A, 256, flag);
  cvt<<<1, 256, 0, stream>>>(bd1, bd1A, 128, flag);
  cvt<<<32, 256, 0, stream>>>(wd2, wd2A, 8192, flag);
  cvt<<<1, 256, 0, stream>>>(bd2, bd2A, 64, flag);
  cvt<<<1, 256, 0, stream>>>(wd3, wd3A, 64, flag);
  cvt<<<1, 256, 0, stream>>>(bd3, bd3A, 1, flag);

  int totpack = 256*2304*2 + 256*512*2 + 128*768;
  pack_weights<<<(totpack + 255) / 256, 256, 0, stream>>>(
      bases1, root1, w2_rel, w2_root, bases3, root3, w4_rel, w4_root, wd1,
      B1t, B3t, B2t, B4t, D1t, flag);
  build_x<<<(N * 64 + 255) / 256, 256, 0, stream>>>(enc, speaker, spkA, X, N, flag);
  edge_hist<<<(E + 255) / 256, 256, 0, stream>>>(ei, et, est, cnt_dst, inv1, inv3, E);
  scan_base<<<1, 1024, 0, stream>>>(cnt_dst, basep, N);
  edge_scatter<<<(E + 255) / 256, 256, 0, stream>>>(ei, et, est, basep, cursor, esorted, E);
  invert_counts<<<(N * 16 + 255) / 256, 256, 0, stream>>>(inv1, inv3, N * 16);

  int nb4 = (N + 3) / 4;
  int gxN = (N + 127) / 128;

  // conv1 (RGCN, etype bits 17..20), chunked over Mix
  for (int n0 = 0; n0 < N; n0 += chunk_rows) {
    int CR = (N - n0 < chunk_rows) ? (N - n0) : chunk_rows;
    rgcn_agg<<<(CR + 3) / 4, 256, 0, stream>>>(esorted, basep, X, comp1A,
                                               (const float*)inv1, Mixblk, 17, n0, CR);
    gemm_ms<<<dim3((CR + 127) / 128, 2), 256, 0, stream>>>(
        Mixblk, 2048, X + (size_t)n0 * 256, 256, (const u16*)nullptr, 0,
        2048, 2304, B1t, b1A, hA + (size_t)n0 * 256, 256, CR, 2304, 0);
  }
  // gconv2
  gconv_agg<<<nb4, 256, 0, stream>>>(esorted, basep, hA, AggB, N);
  gemm_ms<<<dim3(gxN, 2), 256, 0, stream>>>(
      AggB, 256, hA, 256, (const u16*)nullptr, 0,
      256, 512, B2t, b2A, hB, 256, N, 512, 0);

  // conv3 (RGCN, edge_speaker_type bits 21..24)
  for (int n0 = 0; n0 < N; n0 += chunk_rows) {
    int CR = (N - n0 < chunk_rows) ? (N - n0) : chunk_rows;
    rgcn_agg<<<(CR + 3) / 4, 256, 0, stream>>>(esorted, basep, X, comp3A,
                                               (const float*)inv3, Mixblk, 21, n0, CR);
    gemm_ms<<<dim3((CR + 127) / 128, 2), 256, 0, stream>>>(
        Mixblk, 2048, X + (size_t)n0 * 256, 256, (const u16*)nullptr, 0,
        2048, 2304, B3t, b3A, hA + (size_t)n0 * 256, 256, CR, 2304, 0);
  }
  // gconv4
  gconv_agg<<<nb4, 256, 0, stream>>>(esorted, basep, hA, AggB, N);
  // X is dead now: reuse its buffer as the bf16 copy of enc for the MLP GEMM
  cvt<<<(N * 256 + 255) / 256, 256, 0, stream>>>(enc, X, N * 256, flag);
  gemm_ms<<<dim3(gxN, 2), 256, 0, stream>>>(
      AggB, 256, hA, 256, (const u16*)nullptr, 0,
      256, 512, B4t, b4A, hC, 256, N, 512, 0);

  // MLP: [enc | h1 | h2] @ wd1 (+relu) -> h1m (AggB region, now dead)
  gemm_ms<<<dim3(gxN, 1), 256, 0, stream>>>(
      X, 256, hB, 256, hC, 256,
      256, 512, D1t, bd1A, h1m, 128, N, 768, 1);
  mlp_tail<<<nb4, 256, 0, stream>>>(h1m, wd2A, bd2A, wd3A, bd3A, d_out, N, flag);

  // diagnostics: only writes if a stage produced all-zero bits (never when correct)
  probe_zero<<<1, 256, 0, stream>>>(X, Mixblk, hA, hB, h1m, d_out, flag);
}

// Round 5
// 1110.885 us; speedup vs baseline: 1.1232x; 1.1232x over previous
//
#include <hip/hip_runtime.h>
#include <stdint.h>

// PreEncodedGCN on MI355X — round 5.
// vs r4: (1) single-block scan -> 3-phase parallel scan; (2) GEMM grid
// XCD-pair swizzle (bm,bn) pairs 8 blockIdx apart for L2 A-slice reuse;
// (3) 12 small cvt launches -> 1 batched kernel; 4 memsets -> 1; enc cvt x4.

typedef unsigned short u16;
typedef __attribute__((ext_vector_type(4))) float f32x4;
typedef __attribute__((ext_vector_type(8))) short short8;

__device__ __forceinline__ float b2f(u16 u){
  union { uint32_t i; float f; } v; v.i = ((uint32_t)u) << 16; return v.f;
}
__device__ __forceinline__ u16 f2b(float f){
  union { float f; uint32_t i; } v; v.f = f;
  uint32_t u = v.i;
  return (u16)((u + 0x7FFFu + ((u >> 16) & 1u)) >> 16);
}
__device__ __forceinline__ u16 rdw(const void* p, size_t i, int f32){
  return f32 ? f2b(((const float*)p)[i]) : ((const u16*)p)[i];
}

// ---------------- dtype detector: 1 = fp32, 0 = bf16 ------------------------
__global__ void detect_dtype(const u16* enc16, int* flag){
  __shared__ int cnt;
  if (threadIdx.x == 0) cnt = 0;
  __syncthreads();
  unsigned u = enc16[threadIdx.x * 2];
  int e = (u >> 7) & 0xFF;
  if (e >= 100 && e <= 140) atomicAdd(&cnt, 1);
  __syncthreads();
  if (threadIdx.x == 0) flag[0] = (cnt < 128) ? 1 : 0;
}

// ---------------- batched small-weight conversion ---------------------------
// arena: spk@0(1024) c1@1024(128) c3@1152(128) b1@1280 b2@1536 b3@1792
// b4@2048(256ea) bd1@2304(128) wd2@2432(8192) bd2@10624(64) wd3@10688(64)
// bd3@10752(1)
__global__ void cvt_small(const void* spk, const void* c1, const void* c3,
                          const void* b1, const void* b2, const void* b3,
                          const void* b4, const void* bd1, const void* wd2,
                          const void* bd2, const void* wd3, const void* bd3,
                          u16* __restrict__ arena, const int* __restrict__ flag)
{
  int f = *flag;
  int i = blockIdx.x * blockDim.x + threadIdx.x;
  if (i < 1024) { arena[i] = rdw(spk, i, f); return; } i -= 1024;
  if (i < 128)  { arena[1024 + i] = rdw(c1, i, f); return; } i -= 128;
  if (i < 128)  { arena[1152 + i] = rdw(c3, i, f); return; } i -= 128;
  if (i < 256)  { arena[1280 + i] = rdw(b1, i, f); return; } i -= 256;
  if (i < 256)  { arena[1536 + i] = rdw(b2, i, f); return; } i -= 256;
  if (i < 256)  { arena[1792 + i] = rdw(b3, i, f); return; } i -= 256;
  if (i < 256)  { arena[2048 + i] = rdw(b4, i, f); return; } i -= 256;
  if (i < 128)  { arena[2304 + i] = rdw(bd1, i, f); return; } i -= 128;
  if (i < 8192) { arena[2432 + i] = rdw(wd2, i, f); return; } i -= 8192;
  if (i < 64)   { arena[10624 + i] = rdw(bd2, i, f); return; } i -= 64;
  if (i < 64)   { arena[10688 + i] = rdw(wd3, i, f); return; } i -= 64;
  if (i < 1)    { arena[10752 + i] = rdw(bd3, i, f); }
}

// ---------------- vectorized convert (n multiple of 4) ----------------------
__global__ void cvt4(const void* __restrict__ in, u16* __restrict__ out, int n,
                     const int* __restrict__ flag){
  int i = (blockIdx.x * blockDim.x + threadIdx.x) * 4;
  if (i >= n) return;
  ushort4 o;
  if (*flag) {
    float4 v = *(const float4*)((const float*)in + i);
    o.x = f2b(v.x); o.y = f2b(v.y); o.z = f2b(v.z); o.w = f2b(v.w);
  } else {
    o = *(const ushort4*)((const u16*)in + i);
  }
  *(ushort4*)(out + i) = o;
}

// ---------------- weight packing: transpose B matrices to [NOUT, K] ----------
__global__ void pack_weights(const void* __restrict__ bases1, const void* __restrict__ root1,
                             const void* __restrict__ w2_rel, const void* __restrict__ w2_root,
                             const void* __restrict__ bases3, const void* __restrict__ root3,
                             const void* __restrict__ w4_rel, const void* __restrict__ w4_root,
                             const void* __restrict__ wd1,
                             u16* __restrict__ B1t, u16* __restrict__ B3t,
                             u16* __restrict__ B2t, u16* __restrict__ B4t,
                             u16* __restrict__ D1t, const int* __restrict__ flag)
{
  int f = *flag;
  int idx = blockIdx.x * blockDim.x + threadIdx.x;
  if (idx < 256*2304) { int o = idx / 2304, k = idx % 2304;
    B1t[idx] = (k < 2048) ? rdw(bases1, k*256 + o, f) : rdw(root1, (k-2048)*256 + o, f); return; }
  idx -= 256*2304;
  if (idx < 256*2304) { int o = idx / 2304, k = idx % 2304;
    B3t[idx] = (k < 2048) ? rdw(bases3, k*256 + o, f) : rdw(root3, (k-2048)*256 + o, f); return; }
  idx -= 256*2304;
  if (idx < 256*512) { int o = idx / 512, k = idx % 512;
    B2t[idx] = (k < 256) ? rdw(w2_rel, k*256 + o, f) : rdw(w2_root, (k-256)*256 + o, f); return; }
  idx -= 256*512;
  if (idx < 256*512) { int o = idx / 512, k = idx % 512;
    B4t[idx] = (k < 256) ? rdw(w4_rel, k*256 + o, f) : rdw(w4_root, (k-256)*256 + o, f); return; }
  idx -= 256*512;
  if (idx < 128*768) { int o = idx / 768, k = idx % 768;
    D1t[idx] = rdw(wd1, k*128 + o, f); }
}

// ---------------- x = encoding + spk_table[speaker] -------------------------
__global__ void build_x(const void* __restrict__ enc, const int* __restrict__ speaker,
                        const u16* __restrict__ spkA /* bf16 [4,256] */,
                        u16* __restrict__ X /* [N,256] */, int N,
                        const int* __restrict__ flag)
{
  int f = *flag;
  int idx = blockIdx.x * blockDim.x + threadIdx.x;
  if (idx >= N * 64) return;
  int n = idx >> 6, c = (idx & 63) * 4;
  int sp = speaker[n];
  ushort4 sv = *(const ushort4*)(spkA + (size_t)sp*256 + c);
  float e0, e1, e2, e3;
  if (f) {
    float4 ev = *(const float4*)((const float*)enc + (size_t)n*256 + c);
    e0 = ev.x; e1 = ev.y; e2 = ev.z; e3 = ev.w;
  } else {
    ushort4 ev = *(const ushort4*)((const u16*)enc + (size_t)n*256 + c);
    e0 = b2f(ev.x); e1 = b2f(ev.y); e2 = b2f(ev.z); e3 = b2f(ev.w);
  }
  ushort4 xv;
  xv.x = f2b(e0 + b2f(sv.x));
  xv.y = f2b(e1 + b2f(sv.y));
  xv.z = f2b(e2 + b2f(sv.z));
  xv.w = f2b(e3 + b2f(sv.w));
  *(ushort4*)(X + (size_t)n*256 + c) = xv;
}

// ---------------- edge histogram (dst degree + per-(dst,rel) counts) ---------
__global__ void edge_hist(const int* __restrict__ ei, const int* __restrict__ et,
                          const int* __restrict__ est,
                          int* cnt_dst, int* cnt1, int* cnt3, int E)
{
  int e = blockIdx.x * blockDim.x + threadIdx.x;
  if (e >= E) return;
  int d = ei[E + e];
  atomicAdd(&cnt_dst[d], 1);
  atomicAdd(&cnt1[d*16 + et[e]], 1);
  atomicAdd(&cnt3[d*16 + est[e]], 1);
}

// ---------------- 3-phase parallel exclusive scan ---------------------------
__global__ void scan_p1(const int* __restrict__ cnt, int* __restrict__ partial,
                        int* __restrict__ bsum, int N)
{
  __shared__ int s[256];
  int t = threadIdx.x;
  int g = blockIdx.x * 256 + t;
  int v = (g < N) ? cnt[g] : 0;
  s[t] = v; __syncthreads();
  #pragma unroll
  for (int off = 1; off < 256; off <<= 1) {
    int u = (t >= off) ? s[t - off] : 0;
    __syncthreads();
    s[t] += u;
    __syncthreads();
  }
  partial[g] = s[t];                       // inclusive
  if (t == 255) bsum[blockIdx.x] = s[255];
}

__global__ void scan_p2(int* __restrict__ bsum, int nb)
{
  __shared__ int s[1024];
  int t = threadIdx.x;
  int v = (t < nb) ? bsum[t] : 0;
  s[t] = v; __syncthreads();
  #pragma unroll
  for (int off = 1; off < 1024; off <<= 1) {
    int u = (t >= off) ? s[t - off] : 0;
    __syncthreads();
    s[t] += u;
    __syncthreads();
  }
  if (t < nb) bsum[t] = s[t] - v;          // exclusive
  if (t == nb - 1) bsum[nb] = s[t];        // total
}

__global__ void scan_p3(const int* __restrict__ cnt, const int* __restrict__ partial,
                        const int* __restrict__ bsum, int* __restrict__ basep, int N)
{
  int g = blockIdx.x * 256 + threadIdx.x;
  if (g < N) basep[g] = partial[g] - cnt[g] + bsum[blockIdx.x];
  if (g == 0) basep[N] = bsum[(N + 255) / 256];
}

// ---------------- scatter edges into dst-sorted order, packed ---------------
__global__ void edge_scatter(const int* __restrict__ ei, const int* __restrict__ et,
                             const int* __restrict__ est, const int* __restrict__ basep,
                             int* cursor, int* __restrict__ esorted, int E)
{
  int e = blockIdx.x * blockDim.x + threadIdx.x;
  if (e >= E) return;
  int d = ei[E + e];
  int pos = basep[d] + atomicAdd(&cursor[d], 1);
  esorted[pos] = ei[e] | (et[e] << 17) | (est[e] << 21);  // src<2^17, 4+4 bits rels
}

// ---------------- counts -> 1/max(cnt,1) in-place (int -> float) ------------
__global__ void invert_counts(int* a, int* b, int total)
{
  int i = blockIdx.x * blockDim.x + threadIdx.x;
  if (i >= total) return;
  int c = a[i]; ((float*)a)[i] = 1.0f / (float)(c > 1 ? c : 1);
  int d = b[i]; ((float*)b)[i] = 1.0f / (float)(d > 1 ? d : 1);
}

// ---------------- RGCN aggregation into basis space: wave per node ----------
__global__ __launch_bounds__(256) void rgcn_agg(
    const int* __restrict__ esorted, const int* __restrict__ basep,
    const u16* __restrict__ X /* [N,256] */,
    const u16* __restrict__ comp /* bf16 [16,8] */,
    const float* __restrict__ inv /* [N,16] */,
    u16* __restrict__ Mix /* [CR,2048] */,
    int shift, int n0, int CR)
{
  __shared__ float scomp[128];
  if (threadIdx.x < 128) scomp[threadIdx.x] = b2f(comp[threadIdx.x]);
  __syncthreads();
  int nl = blockIdx.x * 4 + (threadIdx.x >> 6);
  if (nl >= CR) return;
  int n = n0 + nl;
  int lane = threadIdx.x & 63;
  float acc[8][4] = {};
  int e0 = basep[n], e1 = basep[n + 1];
  for (int e = e0; e < e1; e++) {
    int rec = esorted[e];
    int src = rec & 0x1FFFF;
    int r = (rec >> shift) & 15;
    float iv = inv[n * 16 + r];
    ushort4 xr = *(const ushort4*)(X + (size_t)src * 256 + lane * 4);
    float x0 = b2f(xr.x), x1 = b2f(xr.y), x2 = b2f(xr.z), x3 = b2f(xr.w);
    const float* cp = scomp + r * 8;
    #pragma unroll
    for (int b = 0; b < 8; b++) {
      float w = cp[b] * iv;
      acc[b][0] += w * x0; acc[b][1] += w * x1;
      acc[b][2] += w * x2; acc[b][3] += w * x3;
    }
  }
  #pragma unroll
  for (int b = 0; b < 8; b++) {
    ushort4 o;
    o.x = f2b(acc[b][0]); o.y = f2b(acc[b][1]);
    o.z = f2b(acc[b][2]); o.w = f2b(acc[b][3]);
    *(ushort4*)(Mix + (size_t)nl * 2048 + b * 256 + lane * 4) = o;
  }
}

// ---------------- GraphConv sum-aggregation: wave per node ------------------
__global__ __launch_bounds__(256) void gconv_agg(
    const int* __restrict__ esorted, const int* __restrict__ basep,
    const u16* __restrict__ Hin /* [N,256] */,
    u16* __restrict__ Agg /* [N,256] */, int N)
{
  int n = blockIdx.x * 4 + (threadIdx.x >> 6);
  if (n >= N) return;
  int lane = threadIdx.x & 63;
  float a0 = 0, a1 = 0, a2 = 0, a3 = 0;
  int e0 = basep[n], e1 = basep[n + 1];
  for (int e = e0; e < e1; e++) {
    int src = esorted[e] & 0x1FFFF;
    ushort4 h = *(const ushort4*)(Hin + (size_t)src * 256 + lane * 4);
    a0 += b2f(h.x); a1 += b2f(h.y); a2 += b2f(h.z); a3 += b2f(h.w);
  }
  ushort4 o; o.x = f2b(a0); o.y = f2b(a1); o.z = f2b(a2); o.w = f2b(a3);
  *(ushort4*)(Agg + (size_t)n * 256 + lane * 4) = o;
}

// ------------- multi-source bf16 MFMA GEMM: C = [A0|A1|A2] @ Bt^T + bias ----
// ny==2: XCD-pair swizzle — (bm,bn=0/1) pair lands 8 blockIdx apart (same XCD
// under round-robin) so the second block L2-hits the 128-row A slice.
__global__ __launch_bounds__(256) void gemm_ms(
    const u16* __restrict__ A0, int lda0,
    const u16* __restrict__ A1, int lda1,
    const u16* __restrict__ A2, int lda2,
    int c1, int c2,
    const u16* __restrict__ Bt, /* [NOUT, K] */
    const u16* __restrict__ bias,
    u16* __restrict__ Cout, int ldc,
    int M, int K, int relu, int ny)
{
  constexpr int BK = 64;
  constexpr int LDR = 72;                 // padded row stride (u16)
  __shared__ u16 As[128 * LDR];
  __shared__ u16 Bs[128 * LDR];
  int bi = blockIdx.x;
  int bm, bn;
  if (ny == 2) {
    int g = bi >> 4, r = bi & 15;
    int p = g * 8 + (r & 7);
    bm = p * 128; bn = (r >> 3) * 128;
    if (bm >= M) return;                  // uniform per block — safe
  } else {
    bm = bi * 128; bn = 0;
  }
  int tid = threadIdx.x;
  int wid = tid >> 6, lane = tid & 63;
  int wm = (wid & 1) * 64, wn = (wid >> 1) * 64;
  f32x4 acc[4][4];
  #pragma unroll
  for (int i = 0; i < 4; i++)
    #pragma unroll
    for (int j = 0; j < 4; j++) acc[i][j] = (f32x4)0.0f;

  int sr = tid >> 3;            // 0..31 staging row within 32-row group
  int sc = (tid & 7) * 8;       // 0..56 staging col (u16)
  int lm = lane & 15, quad = lane >> 4;

  for (int k0 = 0; k0 < K; k0 += BK) {
    const u16* srcp; int ldas, kO;   // wave-uniform (k0 uniform)
    if (k0 < c1)      { srcp = A0; ldas = lda0; kO = k0; }
    else if (k0 < c2) { srcp = A1; ldas = lda1; kO = k0 - c1; }
    else              { srcp = A2; ldas = lda2; kO = k0 - c2; }
    short8 va[4], vb[4];
    #pragma unroll
    for (int g = 0; g < 4; g++) {
      int gr = bm + g * 32 + sr; gr = gr < M ? gr : M - 1;
      va[g] = *(const short8*)(srcp + (size_t)gr * ldas + kO + sc);
      int br = bn + g * 32 + sr;
      vb[g] = *(const short8*)(Bt + (size_t)br * K + k0 + sc);
    }
    #pragma unroll
    for (int g = 0; g < 4; g++) {
      *(short8*)(As + (g * 32 + sr) * LDR + sc) = va[g];
      *(short8*)(Bs + (g * 32 + sr) * LDR + sc) = vb[g];
    }
    __syncthreads();
    #pragma unroll
    for (int kk = 0; kk < BK; kk += 32) {
      short8 af[4], bfv[4];
      #pragma unroll
      for (int mi = 0; mi < 4; mi++) {
        int m = wm + mi * 16 + lm;
        af[mi] = *(const short8*)(As + m * LDR + kk + quad * 8);
      }
      #pragma unroll
      for (int ni = 0; ni < 4; ni++) {
        int nn = wn + ni * 16 + lm;
        bfv[ni] = *(const short8*)(Bs + nn * LDR + kk + quad * 8);
      }
      #pragma unroll
      for (int mi = 0; mi < 4; mi++)
        #pragma unroll
        for (int ni = 0; ni < 4; ni++)
          acc[mi][ni] = __builtin_amdgcn_mfma_f32_16x16x32_bf16(
              af[mi], bfv[ni], acc[mi][ni], 0, 0, 0);
    }
    __syncthreads();
  }
  #pragma unroll
  for (int ni = 0; ni < 4; ni++) {
    int gn = bn + wn + ni * 16 + lm;
    float bv = b2f(bias[gn]);
    #pragma unroll
    for (int mi = 0; mi < 4; mi++) {
      int rbase = bm + wm + mi * 16 + quad * 4;
      #pragma unroll
      for (int r = 0; r < 4; r++) {
        int gm = rbase + r;
        if (gm < M) {
          float v = acc[mi][ni][r] + bv;
          if (relu) v = fmaxf(v, 0.f);
          Cout[(size_t)gm * ldc + gn] = f2b(v);
        }
      }
    }
  }
}

// ---------------- fused MLP tail: 128 -> relu 64 -> 1, wave per node --------
__global__ __launch_bounds__(256) void mlp_tail(
    const u16* __restrict__ h1m, const u16* __restrict__ wd2,
    const u16* __restrict__ bd2, const u16* __restrict__ wd3,
    const u16* __restrict__ bd3, void* __restrict__ outp, int N,
    const int* __restrict__ flag)
{
  int n = blockIdx.x * 4 + (threadIdx.x >> 6);
  if (n >= N) return;
  int lane = threadIdx.x & 63;
  float acc = b2f(bd2[lane]);
  const u16* hr = h1m + (size_t)n * 128;
  #pragma unroll 8
  for (int k = 0; k < 128; k++)
    acc += b2f(hr[k]) * b2f(wd2[k * 64 + lane]);
  float r = fmaxf(acc, 0.f) * b2f(wd3[lane]);
  #pragma unroll
  for (int off = 32; off > 0; off >>= 1) r += __shfl_xor(r, off, 64);
  if (lane == 0) {
    float v = r + b2f(bd3[0]);
    if (*flag) ((float*)outp)[n] = v;
    else       ((u16*)outp)[n] = f2b(v);
  }
}

// ---------------- zero-detection probe (writes only on all-zero buffers) ----
__global__ void probe_zero(const u16* __restrict__ X, const u16* __restrict__ Mix,
                           const u16* __restrict__ hA, const u16* __restrict__ hB,
                           const u16* __restrict__ h1m,
                           void* __restrict__ outp, const int* __restrict__ flag)
{
  __shared__ int nz[5];
  int t = threadIdx.x;
  if (t < 5) nz[t] = 0;
  __syncthreads();
  int a = 0, b = 0, c = 0, d = 0, e = 0;
  for (int i = t; i < 4096; i += 256) {
    a |= X[i]; b |= Mix[i]; c |= hA[i]; d |= hB[i]; e |= h1m[i];
  }
  if (a) atomicOr(&nz[0], 1);
  if (b) atomicOr(&nz[1], 1);
  if (c) atomicOr(&nz[2], 1);
  if (d) atomicOr(&nz[3], 1);
  if (e) atomicOr(&nz[4], 1);
  __syncthreads();
  if (t == 0) {
    int f = *flag;
    auto wr = [&](int idx, float val){
      if (f) ((float*)outp)[idx] = val; else ((u16*)outp)[idx] = f2b(val);
    };
    if (!nz[0]) wr(0, 9000.f);
    if (!nz[1]) wr(1, 8000.f);
    if (!nz[2]) wr(2, 7000.f);
    if (!nz[4]) wr(3, 6000.f);
    if (!nz[3]) wr(4, 5000.f);
  }
}

__global__ void sentinel(u16* out, int n, float code){
  int i = blockIdx.x * blockDim.x + threadIdx.x;
  if (i < n) out[i] = f2b(code);
}

extern "C" void kernel_launch(void* const* d_in, const int* in_sizes, int n_in,
                              void* d_out, int out_size, void* d_ws, size_t ws_size,
                              hipStream_t stream)
{
  const void* enc     = d_in[0];
  const int* speaker  = (const int*)d_in[1];
  const int* ei       = (const int*)d_in[2];
  const int* et       = (const int*)d_in[3];
  const int* est      = (const int*)d_in[4];
  const void* spk_tab = d_in[5];
  const void* comp1   = d_in[6];
  const void* bases1  = d_in[7];
  const void* root1   = d_in[8];
  const void* b1      = d_in[9];
  const void* w2_rel  = d_in[10];
  const void* b2      = d_in[11];
  const void* w2_root = d_in[12];
  const void* comp3   = d_in[13];
  const void* bases3  = d_in[14];
  const void* root3   = d_in[15];
  const void* b3      = d_in[16];
  const void* w4_rel  = d_in[17];
  const void* b4      = d_in[18];
  const void* w4_root = d_in[19];
  const void* wd1     = d_in[20];
  const void* bd1     = d_in[21];
  const void* wd2     = d_in[22];
  const void* bd2     = d_in[23];
  const void* wd3     = d_in[24];
  const void* bd3     = d_in[25];

  int N = in_sizes[1];     // 60000
  int E = in_sizes[3];     // 480000
  int nb = (N + 255) / 256;

  char* ws = (char*)d_ws;
  size_t off = 0;
  auto alloc = [&](size_t bytes) -> char* {
    char* p = ws + off; off = (off + bytes + 255) & ~(size_t)255; return p;
  };
  u16* X    = (u16*)alloc((size_t)N * 256 * 2);   // x = enc+spk; later bf16 enc
  u16* hA   = (u16*)alloc((size_t)N * 256 * 2);   // RGCN outputs (reused)
  u16* hB   = (u16*)alloc((size_t)N * 256 * 2);   // h1 final
  u16* hC   = (u16*)alloc((size_t)N * 256 * 2);   // h2 final
  u16* AggB = (u16*)alloc((size_t)N * 256 * 2);   // gconv agg; aliased by h1m
  u16* h1m  = AggB;
  u16* B1t  = (u16*)alloc((size_t)256 * 2304 * 2);
  u16* B3t  = (u16*)alloc((size_t)256 * 2304 * 2);
  u16* B2t  = (u16*)alloc((size_t)256 * 512 * 2);
  u16* B4t  = (u16*)alloc((size_t)256 * 512 * 2);
  u16* D1t  = (u16*)alloc((size_t)128 * 768 * 2);
  u16* arena = (u16*)alloc((size_t)11264 * 2);
  int* flag    = (int*)alloc(256);
  // contiguous zero-init region: inv1, inv3, cnt_dst, cursor
  int* inv1    = (int*)alloc((size_t)N * 16 * 4);
  int* inv3    = (int*)alloc((size_t)N * 16 * 4);
  int* cnt_dst = (int*)alloc((size_t)N * 4);
  int* cursor  = (int*)alloc((size_t)N * 4);
  size_t zspan = (size_t)((char*)cursor - (char*)inv1) + (size_t)N * 4;
  int* basep   = (int*)alloc((size_t)(N + 1) * 4);
  int* partial = (int*)alloc((size_t)nb * 256 * 4);
  int* bsum    = (int*)alloc((size_t)2048 * 4);
  int* esorted = (int*)alloc((size_t)E * 4);

  // arena layout (u16 offsets)
  u16* spkA   = arena + 0;
  u16* comp1A = arena + 1024;
  u16* comp3A = arena + 1152;
  u16* b1A    = arena + 1280;
  u16* b2A    = arena + 1536;
  u16* b3A    = arena + 1792;
  u16* b4A    = arena + 2048;
  u16* bd1A   = arena + 2304;
  u16* wd2A   = arena + 2432;
  u16* bd2A   = arena + 10624;
  u16* wd3A   = arena + 10688;
  u16* bd3A   = arena + 10752;

  size_t rem = (ws_size > off) ? (ws_size - off) : 0;
  long crl = (long)(rem / (2048 * 2));
  int chunk_rows = (int)((crl / 128) * 128);
  int Mpad = ((N + 127) / 128) * 128;
  if (chunk_rows > Mpad) chunk_rows = Mpad;

  if (chunk_rows < 128) {
    float code = 2000.0f + (float)(ws_size >> 20);
    sentinel<<<(out_size + 255) / 256, 256, 0, stream>>>((u16*)d_out, out_size, code);
    return;
  }
  u16* Mixblk = (u16*)(ws + off);

  hipMemsetAsync(inv1, 0, zspan, stream);

  detect_dtype<<<1, 256, 0, stream>>>((const u16*)enc, flag);
  cvt_small<<<43, 256, 0, stream>>>(spk_tab, comp1, comp3, b1, b2, b3, b4,
                                    bd1, wd2, bd2, wd3, bd3, arena, flag);

  int totpack = 256*2304*2 + 256*512*2 + 128*768;
  pack_weights<<<(totpack + 255) / 256, 256, 0, stream>>>(
      bases1, root1, w2_rel, w2_root, bases3, root3, w4_rel, w4_root, wd1,
      B1t, B3t, B2t, B4t, D1t, flag);
  build_x<<<(N * 64 + 255) / 256, 256, 0, stream>>>(enc, speaker, spkA, X, N, flag);
  edge_hist<<<(E + 255) / 256, 256, 0, stream>>>(ei, et, est, cnt_dst, inv1, inv3, E);
  scan_p1<<<nb, 256, 0, stream>>>(cnt_dst, partial, bsum, N);
  scan_p2<<<1, 1024, 0, stream>>>(bsum, nb);
  scan_p3<<<nb, 256, 0, stream>>>(cnt_dst, partial, bsum, basep, N);
  edge_scatter<<<(E + 255) / 256, 256, 0, stream>>>(ei, et, est, basep, cursor, esorted, E);
  invert_counts<<<(N * 16 + 255) / 256, 256, 0, stream>>>(inv1, inv3, N * 16);

  int nb4 = (N + 3) / 4;
  int gxN = (N + 127) / 128;
  auto pair_grid = [](int gx) { return ((gx + 7) / 8) * 16; };

  // conv1 (RGCN, etype bits 17..20), chunked over Mix
  for (int n0 = 0; n0 < N; n0 += chunk_rows) {
    int CR = (N - n0 < chunk_rows) ? (N - n0) : chunk_rows;
    rgcn_agg<<<(CR + 3) / 4, 256, 0, stream>>>(esorted, basep, X, comp1A,
                                               (const float*)inv1, Mixblk, 17, n0, CR);
    gemm_ms<<<pair_grid((CR + 127) / 128), 256, 0, stream>>>(
        Mixblk, 2048, X + (size_t)n0 * 256, 256, (const u16*)nullptr, 0,
        2048, 2304, B1t, b1A, hA + (size_t)n0 * 256, 256, CR, 2304, 0, 2);
  }
  // gconv2
  gconv_agg<<<nb4, 256, 0, stream>>>(esorted, basep, hA, AggB, N);
  gemm_ms<<<pair_grid(gxN), 256, 0, stream>>>(
      AggB, 256, hA, 256, (const u16*)nullptr, 0,
      256, 512, B2t, b2A, hB, 256, N, 512, 0, 2);

  // conv3 (RGCN, edge_speaker_type bits 21..24)
  for (int n0 = 0; n0 < N; n0 += chunk_rows) {
    int CR = (N - n0 < chunk_rows) ? (N - n0) : chunk_rows;
    rgcn_agg<<<(CR + 3) / 4, 256, 0, stream>>>(esorted, basep, X, comp3A,
                                               (const float*)inv3, Mixblk, 21, n0, CR);
    gemm_ms<<<pair_grid((CR + 127) / 128), 256, 0, stream>>>(
        Mixblk, 2048, X + (size_t)n0 * 256, 256, (const u16*)nullptr, 0,
        2048, 2304, B3t, b3A, hA + (size_t)n0 * 256, 256, CR, 2304, 0, 2);
  }
  // gconv4
  gconv_agg<<<nb4, 256, 0, stream>>>(esorted, basep, hA, AggB, N);
  // X dead: reuse as bf16 enc for the MLP GEMM
  cvt4<<<(N * 64 + 255) / 256, 256, 0, stream>>>(enc, X, N * 256, flag);
  gemm_ms<<<pair_grid(gxN), 256, 0, stream>>>(
      AggB, 256, hA, 256, (const u16*)nullptr, 0,
      256, 512, B4t, b4A, hC, 256, N, 512, 0, 2);

  // MLP: [enc | h1 | h2] @ wd1 (+relu) -> h1m
  gemm_ms<<<gxN, 256, 0, stream>>>(
      X, 256, hB, 256, hC, 256,
      256, 512, D1t, bd1A, h1m, 128, N, 768, 1, 1);
  mlp_tail<<<nb4, 256, 0, stream>>>(h1m, wd2A, bd2A, wd3A, bd3A, d_out, N, flag);

  probe_zero<<<1, 256, 0, stream>>>(X, Mixblk, hA, hB, h1m, d_out, flag);
}

// Round 6
// 1054.277 us; speedup vs baseline: 1.1835x; 1.0537x over previous
//
#include <hip/hip_runtime.h>
#include <stdint.h>

// PreEncodedGCN on MI355X — round 6.
// vs r5: MLP layer-2 (128->64, relu) moved from scalar-VALU mlp_tail into the
// MFMA GEMM (gemm_ms grew an `nout` guard); new trivial mlp_tail2 does the
// 64->1 dot. probe_zero removed (served its purpose).

typedef unsigned short u16;
typedef __attribute__((ext_vector_type(4))) float f32x4;
typedef __attribute__((ext_vector_type(8))) short short8;

__device__ __forceinline__ float b2f(u16 u){
  union { uint32_t i; float f; } v; v.i = ((uint32_t)u) << 16; return v.f;
}
__device__ __forceinline__ u16 f2b(float f){
  union { float f; uint32_t i; } v; v.f = f;
  uint32_t u = v.i;
  return (u16)((u + 0x7FFFu + ((u >> 16) & 1u)) >> 16);
}
__device__ __forceinline__ u16 rdw(const void* p, size_t i, int f32){
  return f32 ? f2b(((const float*)p)[i]) : ((const u16*)p)[i];
}

// ---------------- dtype detector: 1 = fp32, 0 = bf16 ------------------------
__global__ void detect_dtype(const u16* enc16, int* flag){
  __shared__ int cnt;
  if (threadIdx.x == 0) cnt = 0;
  __syncthreads();
  unsigned u = enc16[threadIdx.x * 2];
  int e = (u >> 7) & 0xFF;
  if (e >= 100 && e <= 140) atomicAdd(&cnt, 1);
  __syncthreads();
  if (threadIdx.x == 0) flag[0] = (cnt < 128) ? 1 : 0;
}

// ---------------- batched small-weight conversion ---------------------------
// arena u16 offsets: spk@0(1024) c1@1024(128) c3@1152(128) b1@1280 b2@1536
// b3@1792 b4@2048(256ea) bd1@2304(128) wd2@2432(8192) bd2@10624(64)
// wd3@10688(64) bd3@10752(1) wd2T@10880(8192, [o*128+k])
__global__ void cvt_small(const void* spk, const void* c1, const void* c3,
                          const void* b1, const void* b2, const void* b3,
                          const void* b4, const void* bd1, const void* wd2,
                          const void* bd2, const void* wd3, const void* bd3,
                          u16* __restrict__ arena, const int* __restrict__ flag)
{
  int f = *flag;
  int i = blockIdx.x * blockDim.x + threadIdx.x;
  if (i < 1024) { arena[i] = rdw(spk, i, f); return; } i -= 1024;
  if (i < 128)  { arena[1024 + i] = rdw(c1, i, f); return; } i -= 128;
  if (i < 128)  { arena[1152 + i] = rdw(c3, i, f); return; } i -= 128;
  if (i < 256)  { arena[1280 + i] = rdw(b1, i, f); return; } i -= 256;
  if (i < 256)  { arena[1536 + i] = rdw(b2, i, f); return; } i -= 256;
  if (i < 256)  { arena[1792 + i] = rdw(b3, i, f); return; } i -= 256;
  if (i < 256)  { arena[2048 + i] = rdw(b4, i, f); return; } i -= 256;
  if (i < 128)  { arena[2304 + i] = rdw(bd1, i, f); return; } i -= 128;
  if (i < 8192) { arena[2432 + i] = rdw(wd2, i, f); return; } i -= 8192;
  if (i < 64)   { arena[10624 + i] = rdw(bd2, i, f); return; } i -= 64;
  if (i < 64)   { arena[10688 + i] = rdw(wd3, i, f); return; } i -= 64;
  if (i < 1)    { arena[10752 + i] = rdw(bd3, i, f); return; } i -= 1;
  if (i < 8192) { int o = i >> 7, k = i & 127;          // wd2T[o,k] = wd2[k,o]
    arena[10880 + i] = rdw(wd2, k * 64 + o, f); }
}

// ---------------- vectorized convert (n multiple of 4) ----------------------
__global__ void cvt4(const void* __restrict__ in, u16* __restrict__ out, int n,
                     const int* __restrict__ flag){
  int i = (blockIdx.x * blockDim.x + threadIdx.x) * 4;
  if (i >= n) return;
  ushort4 o;
  if (*flag) {
    float4 v = *(const float4*)((const float*)in + i);
    o.x = f2b(v.x); o.y = f2b(v.y); o.z = f2b(v.z); o.w = f2b(v.w);
  } else {
    o = *(const ushort4*)((const u16*)in + i);
  }
  *(ushort4*)(out + i) = o;
}

// ---------------- weight packing: transpose B matrices to [NOUT, K] ----------
__global__ void pack_weights(const void* __restrict__ bases1, const void* __restrict__ root1,
                             const void* __restrict__ w2_rel, const void* __restrict__ w2_root,
                             const void* __restrict__ bases3, const void* __restrict__ root3,
                             const void* __restrict__ w4_rel, const void* __restrict__ w4_root,
                             const void* __restrict__ wd1,
                             u16* __restrict__ B1t, u16* __restrict__ B3t,
                             u16* __restrict__ B2t, u16* __restrict__ B4t,
                             u16* __restrict__ D1t, const int* __restrict__ flag)
{
  int f = *flag;
  int idx = blockIdx.x * blockDim.x + threadIdx.x;
  if (idx < 256*2304) { int o = idx / 2304, k = idx % 2304;
    B1t[idx] = (k < 2048) ? rdw(bases1, k*256 + o, f) : rdw(root1, (k-2048)*256 + o, f); return; }
  idx -= 256*2304;
  if (idx < 256*2304) { int o = idx / 2304, k = idx % 2304;
    B3t[idx] = (k < 2048) ? rdw(bases3, k*256 + o, f) : rdw(root3, (k-2048)*256 + o, f); return; }
  idx -= 256*2304;
  if (idx < 256*512) { int o = idx / 512, k = idx % 512;
    B2t[idx] = (k < 256) ? rdw(w2_rel, k*256 + o, f) : rdw(w2_root, (k-256)*256 + o, f); return; }
  idx -= 256*512;
  if (idx < 256*512) { int o = idx / 512, k = idx % 512;
    B4t[idx] = (k < 256) ? rdw(w4_rel, k*256 + o, f) : rdw(w4_root, (k-256)*256 + o, f); return; }
  idx -= 256*512;
  if (idx < 128*768) { int o = idx / 768, k = idx % 768;
    D1t[idx] = rdw(wd1, k*128 + o, f); }
}

// ---------------- x = encoding + spk_table[speaker] -------------------------
__global__ void build_x(const void* __restrict__ enc, const int* __restrict__ speaker,
                        const u16* __restrict__ spkA /* bf16 [4,256] */,
                        u16* __restrict__ X /* [N,256] */, int N,
                        const int* __restrict__ flag)
{
  int f = *flag;
  int idx = blockIdx.x * blockDim.x + threadIdx.x;
  if (idx >= N * 64) return;
  int n = idx >> 6, c = (idx & 63) * 4;
  int sp = speaker[n];
  ushort4 sv = *(const ushort4*)(spkA + (size_t)sp*256 + c);
  float e0, e1, e2, e3;
  if (f) {
    float4 ev = *(const float4*)((const float*)enc + (size_t)n*256 + c);
    e0 = ev.x; e1 = ev.y; e2 = ev.z; e3 = ev.w;
  } else {
    ushort4 ev = *(const ushort4*)((const u16*)enc + (size_t)n*256 + c);
    e0 = b2f(ev.x); e1 = b2f(ev.y); e2 = b2f(ev.z); e3 = b2f(ev.w);
  }
  ushort4 xv;
  xv.x = f2b(e0 + b2f(sv.x));
  xv.y = f2b(e1 + b2f(sv.y));
  xv.z = f2b(e2 + b2f(sv.z));
  xv.w = f2b(e3 + b2f(sv.w));
  *(ushort4*)(X + (size_t)n*256 + c) = xv;
}

// ---------------- edge histogram (dst degree + per-(dst,rel) counts) ---------
__global__ void edge_hist(const int* __restrict__ ei, const int* __restrict__ et,
                          const int* __restrict__ est,
                          int* cnt_dst, int* cnt1, int* cnt3, int E)
{
  int e = blockIdx.x * blockDim.x + threadIdx.x;
  if (e >= E) return;
  int d = ei[E + e];
  atomicAdd(&cnt_dst[d], 1);
  atomicAdd(&cnt1[d*16 + et[e]], 1);
  atomicAdd(&cnt3[d*16 + est[e]], 1);
}

// ---------------- 3-phase parallel exclusive scan ---------------------------
__global__ void scan_p1(const int* __restrict__ cnt, int* __restrict__ partial,
                        int* __restrict__ bsum, int N)
{
  __shared__ int s[256];
  int t = threadIdx.x;
  int g = blockIdx.x * 256 + t;
  int v = (g < N) ? cnt[g] : 0;
  s[t] = v; __syncthreads();
  #pragma unroll
  for (int off = 1; off < 256; off <<= 1) {
    int u = (t >= off) ? s[t - off] : 0;
    __syncthreads();
    s[t] += u;
    __syncthreads();
  }
  partial[g] = s[t];                       // inclusive
  if (t == 255) bsum[blockIdx.x] = s[255];
}

__global__ void scan_p2(int* __restrict__ bsum, int nb)
{
  __shared__ int s[1024];
  int t = threadIdx.x;
  int v = (t < nb) ? bsum[t] : 0;
  s[t] = v; __syncthreads();
  #pragma unroll
  for (int off = 1; off < 1024; off <<= 1) {
    int u = (t >= off) ? s[t - off] : 0;
    __syncthreads();
    s[t] += u;
    __syncthreads();
  }
  if (t < nb) bsum[t] = s[t] - v;          // exclusive
  if (t == nb - 1) bsum[nb] = s[t];        // total
}

__global__ void scan_p3(const int* __restrict__ cnt, const int* __restrict__ partial,
                        const int* __restrict__ bsum, int* __restrict__ basep, int N)
{
  int g = blockIdx.x * 256 + threadIdx.x;
  if (g < N) basep[g] = partial[g] - cnt[g] + bsum[blockIdx.x];
  if (g == 0) basep[N] = bsum[(N + 255) / 256];
}

// ---------------- scatter edges into dst-sorted order, packed ---------------
__global__ void edge_scatter(const int* __restrict__ ei, const int* __restrict__ et,
                             const int* __restrict__ est, const int* __restrict__ basep,
                             int* cursor, int* __restrict__ esorted, int E)
{
  int e = blockIdx.x * blockDim.x + threadIdx.x;
  if (e >= E) return;
  int d = ei[E + e];
  int pos = basep[d] + atomicAdd(&cursor[d], 1);
  esorted[pos] = ei[e] | (et[e] << 17) | (est[e] << 21);  // src<2^17, 4+4 bits rels
}

// ---------------- counts -> 1/max(cnt,1) in-place (int -> float) ------------
__global__ void invert_counts(int* a, int* b, int total)
{
  int i = blockIdx.x * blockDim.x + threadIdx.x;
  if (i >= total) return;
  int c = a[i]; ((float*)a)[i] = 1.0f / (float)(c > 1 ? c : 1);
  int d = b[i]; ((float*)b)[i] = 1.0f / (float)(d > 1 ? d : 1);
}

// ---------------- RGCN aggregation into basis space: wave per node ----------
__global__ __launch_bounds__(256) void rgcn_agg(
    const int* __restrict__ esorted, const int* __restrict__ basep,
    const u16* __restrict__ X /* [N,256] */,
    const u16* __restrict__ comp /* bf16 [16,8] */,
    const float* __restrict__ inv /* [N,16] */,
    u16* __restrict__ Mix /* [CR,2048] */,
    int shift, int n0, int CR)
{
  __shared__ float scomp[128];
  if (threadIdx.x < 128) scomp[threadIdx.x] = b2f(comp[threadIdx.x]);
  __syncthreads();
  int nl = blockIdx.x * 4 + (threadIdx.x >> 6);
  if (nl >= CR) return;
  int n = n0 + nl;
  int lane = threadIdx.x & 63;
  float acc[8][4] = {};
  int e0 = basep[n], e1 = basep[n + 1];
  for (int e = e0; e < e1; e++) {
    int rec = esorted[e];
    int src = rec & 0x1FFFF;
    int r = (rec >> shift) & 15;
    float iv = inv[n * 16 + r];
    ushort4 xr = *(const ushort4*)(X + (size_t)src * 256 + lane * 4);
    float x0 = b2f(xr.x), x1 = b2f(xr.y), x2 = b2f(xr.z), x3 = b2f(xr.w);
    const float* cp = scomp + r * 8;
    #pragma unroll
    for (int b = 0; b < 8; b++) {
      float w = cp[b] * iv;
      acc[b][0] += w * x0; acc[b][1] += w * x1;
      acc[b][2] += w * x2; acc[b][3] += w * x3;
    }
  }
  #pragma unroll
  for (int b = 0; b < 8; b++) {
    ushort4 o;
    o.x = f2b(acc[b][0]); o.y = f2b(acc[b][1]);
    o.z = f2b(acc[b][2]); o.w = f2b(acc[b][3]);
    *(ushort4*)(Mix + (size_t)nl * 2048 + b * 256 + lane * 4) = o;
  }
}

// ---------------- GraphConv sum-aggregation: wave per node ------------------
__global__ __launch_bounds__(256) void gconv_agg(
    const int* __restrict__ esorted, const int* __restrict__ basep,
    const u16* __restrict__ Hin /* [N,256] */,
    u16* __restrict__ Agg /* [N,256] */, int N)
{
  int n = blockIdx.x * 4 + (threadIdx.x >> 6);
  if (n >= N) return;
  int lane = threadIdx.x & 63;
  float a0 = 0, a1 = 0, a2 = 0, a3 = 0;
  int e0 = basep[n], e1 = basep[n + 1];
  for (int e = e0; e < e1; e++) {
    int src = esorted[e] & 0x1FFFF;
    ushort4 h = *(const ushort4*)(Hin + (size_t)src * 256 + lane * 4);
    a0 += b2f(h.x); a1 += b2f(h.y); a2 += b2f(h.z); a3 += b2f(h.w);
  }
  ushort4 o; o.x = f2b(a0); o.y = f2b(a1); o.z = f2b(a2); o.w = f2b(a3);
  *(ushort4*)(Agg + (size_t)n * 256 + lane * 4) = o;
}

// ------------- multi-source bf16 MFMA GEMM: C = [A0|A1|A2] @ Bt^T + bias ----
// ny==2: XCD-pair swizzle — (bm,bn=0/1) pairs 8 blockIdx apart (same XCD
// under round-robin) so the second block L2-hits the 128-row A slice.
// nout: logical NOUT (B rows / bias entries / valid C cols) — may be < 128.
__global__ __launch_bounds__(256) void gemm_ms(
    const u16* __restrict__ A0, int lda0,
    const u16* __restrict__ A1, int lda1,
    const u16* __restrict__ A2, int lda2,
    int c1, int c2,
    const u16* __restrict__ Bt, /* [nout, K] */
    const u16* __restrict__ bias,
    u16* __restrict__ Cout, int ldc,
    int M, int K, int relu, int ny, int nout)
{
  constexpr int BK = 64;
  constexpr int LDR = 72;                 // padded row stride (u16)
  __shared__ u16 As[128 * LDR];
  __shared__ u16 Bs[128 * LDR];
  int bi = blockIdx.x;
  int bm, bn;
  if (ny == 2) {
    int g = bi >> 4, r = bi & 15;
    int p = g * 8 + (r & 7);
    bm = p * 128; bn = (r >> 3) * 128;
    if (bm >= M) return;                  // uniform per block — safe
  } else {
    bm = bi * 128; bn = 0;
  }
  int tid = threadIdx.x;
  int wid = tid >> 6, lane = tid & 63;
  int wm = (wid & 1) * 64, wn = (wid >> 1) * 64;
  f32x4 acc[4][4];
  #pragma unroll
  for (int i = 0; i < 4; i++)
    #pragma unroll
    for (int j = 0; j < 4; j++) acc[i][j] = (f32x4)0.0f;

  int sr = tid >> 3;            // 0..31 staging row within 32-row group
  int sc = (tid & 7) * 8;       // 0..56 staging col (u16)
  int lm = lane & 15, quad = lane >> 4;

  for (int k0 = 0; k0 < K; k0 += BK) {
    const u16* srcp; int ldas, kO;   // wave-uniform (k0 uniform)
    if (k0 < c1)      { srcp = A0; ldas = lda0; kO = k0; }
    else if (k0 < c2) { srcp = A1; ldas = lda1; kO = k0 - c1; }
    else              { srcp = A2; ldas = lda2; kO = k0 - c2; }
    short8 va[4], vb[4];
    #pragma unroll
    for (int g = 0; g < 4; g++) {
      int gr = bm + g * 32 + sr; gr = gr < M ? gr : M - 1;
      va[g] = *(const short8*)(srcp + (size_t)gr * ldas + kO + sc);
      int br = bn + g * 32 + sr; br = br < nout ? br : nout - 1;
      vb[g] = *(const short8*)(Bt + (size_t)br * K + k0 + sc);
    }
    #pragma unroll
    for (int g = 0; g < 4; g++) {
      *(short8*)(As + (g * 32 + sr) * LDR + sc) = va[g];
      *(short8*)(Bs + (g * 32 + sr) * LDR + sc) = vb[g];
    }
    __syncthreads();
    #pragma unroll
    for (int kk = 0; kk < BK; kk += 32) {
      short8 af[4], bfv[4];
      #pragma unroll
      for (int mi = 0; mi < 4; mi++) {
        int m = wm + mi * 16 + lm;
        af[mi] = *(const short8*)(As + m * LDR + kk + quad * 8);
      }
      #pragma unroll
      for (int ni = 0; ni < 4; ni++) {
        int nn = wn + ni * 16 + lm;
        bfv[ni] = *(const short8*)(Bs + nn * LDR + kk + quad * 8);
      }
      #pragma unroll
      for (int mi = 0; mi < 4; mi++)
        #pragma unroll
        for (int ni = 0; ni < 4; ni++)
          acc[mi][ni] = __builtin_amdgcn_mfma_f32_16x16x32_bf16(
              af[mi], bfv[ni], acc[mi][ni], 0, 0, 0);
    }
    __syncthreads();
  }
  #pragma unroll
  for (int ni = 0; ni < 4; ni++) {
    int gn = bn + wn + ni * 16 + lm;
    int gb = gn < nout ? gn : nout - 1;
    float bv = b2f(bias[gb]);
    #pragma unroll
    for (int mi = 0; mi < 4; mi++) {
      int rbase = bm + wm + mi * 16 + quad * 4;
      #pragma unroll
      for (int r = 0; r < 4; r++) {
        int gm = rbase + r;
        if (gm < M && gn < nout) {
          float v = acc[mi][ni][r] + bv;
          if (relu) v = fmaxf(v, 0.f);
          Cout[(size_t)gm * ldc + gn] = f2b(v);
        }
      }
    }
  }
}

// ---------------- final dot: out[n] = sum_o h2m[n,o]*wd3[o] + bd3 -----------
// h2m already relu'd by the GEMM epilogue.
__global__ __launch_bounds__(256) void mlp_tail2(
    const u16* __restrict__ h2m, const u16* __restrict__ wd3,
    const u16* __restrict__ bd3, void* __restrict__ outp, int N,
    const int* __restrict__ flag)
{
  int n = blockIdx.x * 4 + (threadIdx.x >> 6);
  if (n >= N) return;
  int lane = threadIdx.x & 63;
  float r = b2f(h2m[(size_t)n * 64 + lane]) * b2f(wd3[lane]);
  #pragma unroll
  for (int off = 32; off > 0; off >>= 1) r += __shfl_xor(r, off, 64);
  if (lane == 0) {
    float v = r + b2f(bd3[0]);
    if (*flag) ((float*)outp)[n] = v;
    else       ((u16*)outp)[n] = f2b(v);
  }
}

__global__ void sentinel(u16* out, int n, float code){
  int i = blockIdx.x * blockDim.x + threadIdx.x;
  if (i < n) out[i] = f2b(code);
}

extern "C" void kernel_launch(void* const* d_in, const int* in_sizes, int n_in,
                              void* d_out, int out_size, void* d_ws, size_t ws_size,
                              hipStream_t stream)
{
  const void* enc     = d_in[0];
  const int* speaker  = (const int*)d_in[1];
  const int* ei       = (const int*)d_in[2];
  const int* et       = (const int*)d_in[3];
  const int* est      = (const int*)d_in[4];
  const void* spk_tab = d_in[5];
  const void* comp1   = d_in[6];
  const void* bases1  = d_in[7];
  const void* root1   = d_in[8];
  const void* b1      = d_in[9];
  const void* w2_rel  = d_in[10];
  const void* b2      = d_in[11];
  const void* w2_root = d_in[12];
  const void* comp3   = d_in[13];
  const void* bases3  = d_in[14];
  const void* root3   = d_in[15];
  const void* b3      = d_in[16];
  const void* w4_rel  = d_in[17];
  const void* b4      = d_in[18];
  const void* w4_root = d_in[19];
  const void* wd1     = d_in[20];
  const void* bd1     = d_in[21];
  const void* wd2     = d_in[22];
  const void* bd2     = d_in[23];
  const void* wd3     = d_in[24];
  const void* bd3     = d_in[25];

  int N = in_sizes[1];     // 60000
  int E = in_sizes[3];     // 480000
  int nb = (N + 255) / 256;

  char* ws = (char*)d_ws;
  size_t off = 0;
  auto alloc = [&](size_t bytes) -> char* {
    char* p = ws + off; off = (off + bytes + 255) & ~(size_t)255; return p;
  };
  u16* X    = (u16*)alloc((size_t)N * 256 * 2);   // x = enc+spk; later bf16 enc
  u16* hA   = (u16*)alloc((size_t)N * 256 * 2);   // RGCN outputs (reused)
  u16* hB   = (u16*)alloc((size_t)N * 256 * 2);   // h1 final
  u16* hC   = (u16*)alloc((size_t)N * 256 * 2);   // h2 final
  u16* AggB = (u16*)alloc((size_t)N * 256 * 2);   // gconv agg; aliased below
  u16* h1m  = AggB;                                // [N,128] after AggB dead
  u16* h2m  = AggB + (size_t)N * 128;              // [N,64]
  u16* B1t  = (u16*)alloc((size_t)256 * 2304 * 2);
  u16* B3t  = (u16*)alloc((size_t)256 * 2304 * 2);
  u16* B2t  = (u16*)alloc((size_t)256 * 512 * 2);
  u16* B4t  = (u16*)alloc((size_t)256 * 512 * 2);
  u16* D1t  = (u16*)alloc((size_t)128 * 768 * 2);
  u16* arena = (u16*)alloc((size_t)20480 * 2);
  int* flag    = (int*)alloc(256);
  // contiguous zero-init region: inv1, inv3, cnt_dst, cursor
  int* inv1    = (int*)alloc((size_t)N * 16 * 4);
  int* inv3    = (int*)alloc((size_t)N * 16 * 4);
  int* cnt_dst = (int*)alloc((size_t)N * 4);
  int* cursor  = (int*)alloc((size_t)N * 4);
  size_t zspan = (size_t)((char*)cursor - (char*)inv1) + (size_t)N * 4;
  int* basep   = (int*)alloc((size_t)(N + 1) * 4);
  int* partial = (int*)alloc((size_t)nb * 256 * 4);
  int* bsum    = (int*)alloc((size_t)2048 * 4);
  int* esorted = (int*)alloc((size_t)E * 4);

  // arena layout (u16 offsets)
  u16* spkA   = arena + 0;
  u16* comp1A = arena + 1024;
  u16* comp3A = arena + 1152;
  u16* b1A    = arena + 1280;
  u16* b2A    = arena + 1536;
  u16* b3A    = arena + 1792;
  u16* b4A    = arena + 2048;
  u16* bd1A   = arena + 2304;
  u16* bd2A   = arena + 10624;
  u16* wd3A   = arena + 10688;
  u16* bd3A   = arena + 10752;
  u16* wd2T   = arena + 10880;   // [64,128] transposed layer-2 weights

  size_t rem = (ws_size > off) ? (ws_size - off) : 0;
  long crl = (long)(rem / (2048 * 2));
  int chunk_rows = (int)((crl / 128) * 128);
  int Mpad = ((N + 127) / 128) * 128;
  if (chunk_rows > Mpad) chunk_rows = Mpad;

  if (chunk_rows < 128) {
    float code = 2000.0f + (float)(ws_size >> 20);
    sentinel<<<(out_size + 255) / 256, 256, 0, stream>>>((u16*)d_out, out_size, code);
    return;
  }
  u16* Mixblk = (u16*)(ws + off);

  hipMemsetAsync(inv1, 0, zspan, stream);

  detect_dtype<<<1, 256, 0, stream>>>((const u16*)enc, flag);
  cvt_small<<<75, 256, 0, stream>>>(spk_tab, comp1, comp3, b1, b2, b3, b4,
                                    bd1, wd2, bd2, wd3, bd3, arena, flag);

  int totpack = 256*2304*2 + 256*512*2 + 128*768;
  pack_weights<<<(totpack + 255) / 256, 256, 0, stream>>>(
      bases1, root1, w2_rel, w2_root, bases3, root3, w4_rel, w4_root, wd1,
      B1t, B3t, B2t, B4t, D1t, flag);
  build_x<<<(N * 64 + 255) / 256, 256, 0, stream>>>(enc, speaker, spkA, X, N, flag);
  edge_hist<<<(E + 255) / 256, 256, 0, stream>>>(ei, et, est, cnt_dst, inv1, inv3, E);
  scan_p1<<<nb, 256, 0, stream>>>(cnt_dst, partial, bsum, N);
  scan_p2<<<1, 1024, 0, stream>>>(bsum, nb);
  scan_p3<<<nb, 256, 0, stream>>>(cnt_dst, partial, bsum, basep, N);
  edge_scatter<<<(E + 255) / 256, 256, 0, stream>>>(ei, et, est, basep, cursor, esorted, E);
  invert_counts<<<(N * 16 + 255) / 256, 256, 0, stream>>>(inv1, inv3, N * 16);

  int nb4 = (N + 3) / 4;
  int gxN = (N + 127) / 128;
  auto pair_grid = [](int gx) { return ((gx + 7) / 8) * 16; };

  // conv1 (RGCN, etype bits 17..20), chunked over Mix
  for (int n0 = 0; n0 < N; n0 += chunk_rows) {
    int CR = (N - n0 < chunk_rows) ? (N - n0) : chunk_rows;
    rgcn_agg<<<(CR + 3) / 4, 256, 0, stream>>>(esorted, basep, X, comp1A,
                                               (const float*)inv1, Mixblk, 17, n0, CR);
    gemm_ms<<<pair_grid((CR + 127) / 128), 256, 0, stream>>>(
        Mixblk, 2048, X + (size_t)n0 * 256, 256, (const u16*)nullptr, 0,
        2048, 2304, B1t, b1A, hA + (size_t)n0 * 256, 256, CR, 2304, 0, 2, 256);
  }
  // gconv2
  gconv_agg<<<nb4, 256, 0, stream>>>(esorted, basep, hA, AggB, N);
  gemm_ms<<<pair_grid(gxN), 256, 0, stream>>>(
      AggB, 256, hA, 256, (const u16*)nullptr, 0,
      256, 512, B2t, b2A, hB, 256, N, 512, 0, 2, 256);

  // conv3 (RGCN, edge_speaker_type bits 21..24)
  for (int n0 = 0; n0 < N; n0 += chunk_rows) {
    int CR = (N - n0 < chunk_rows) ? (N - n0) : chunk_rows;
    rgcn_agg<<<(CR + 3) / 4, 256, 0, stream>>>(esorted, basep, X, comp3A,
                                               (const float*)inv3, Mixblk, 21, n0, CR);
    gemm_ms<<<pair_grid((CR + 127) / 128), 256, 0, stream>>>(
        Mixblk, 2048, X + (size_t)n0 * 256, 256, (const u16*)nullptr, 0,
        2048, 2304, B3t, b3A, hA + (size_t)n0 * 256, 256, CR, 2304, 0, 2, 256);
  }
  // gconv4
  gconv_agg<<<nb4, 256, 0, stream>>>(esorted, basep, hA, AggB, N);
  // X dead: reuse as bf16 enc for the MLP GEMM
  cvt4<<<(N * 64 + 255) / 256, 256, 0, stream>>>(enc, X, N * 256, flag);
  gemm_ms<<<pair_grid(gxN), 256, 0, stream>>>(
      AggB, 256, hA, 256, (const u16*)nullptr, 0,
      256, 512, B4t, b4A, hC, 256, N, 512, 0, 2, 256);

  // MLP layer 1: [enc | h1 | h2] @ wd1 (+bd1, relu) -> h1m [N,128]
  gemm_ms<<<gxN, 256, 0, stream>>>(
      X, 256, hB, 256, hC, 256,
      256, 512, D1t, bd1A, h1m, 128, N, 768, 1, 1, 128);
  // MLP layer 2: h1m @ wd2 (+bd2, relu) -> h2m [N,64]  (MFMA, nout=64)
  gemm_ms<<<gxN, 256, 0, stream>>>(
      h1m, 128, (const u16*)nullptr, 0, (const u16*)nullptr, 0,
      128, 128, wd2T, bd2A, h2m, 64, N, 128, 1, 1, 64);
  // MLP layer 3: dot with wd3 + bd3
  mlp_tail2<<<nb4, 256, 0, stream>>>(h2m, wd3A, bd3A, d_out, N, flag);
}

// Round 7
// 1010.875 us; speedup vs baseline: 1.2343x; 1.0429x over previous
//
#include <hip/hip_runtime.h>
#include <stdint.h>

// PreEncodedGCN on MI355X — round 7.
// vs r6: (1) GEMM re-tiled 128x32 (8 n-blocks, XCD-grouped same-m) to fix the
// latency-bound 0.9-block/CU conv GEMM; (2) conv1+conv3 aggregation merged
// into one edge pass (shared X gathers) with in-wave per-(dst,rel) counts
// (kills cnt1/cnt3 atomics + invert_counts); (3) dual-conv GEMM in one launch;
// (4) gconv_agg 16B/lane, 2 edges/wave-iter.

typedef unsigned short u16;
typedef __attribute__((ext_vector_type(4))) float f32x4;
typedef __attribute__((ext_vector_type(8))) short short8;

__device__ __forceinline__ float b2f(u16 u){
  union { uint32_t i; float f; } v; v.i = ((uint32_t)u) << 16; return v.f;
}
__device__ __forceinline__ u16 f2b(float f){
  union { float f; uint32_t i; } v; v.f = f;
  uint32_t u = v.i;
  return (u16)((u + 0x7FFFu + ((u >> 16) & 1u)) >> 16);
}
__device__ __forceinline__ u16 rdw(const void* p, size_t i, int f32){
  return f32 ? f2b(((const float*)p)[i]) : ((const u16*)p)[i];
}

// ---------------- dtype detector: 1 = fp32, 0 = bf16 ------------------------
__global__ void detect_dtype(const u16* enc16, int* flag){
  __shared__ int cnt;
  if (threadIdx.x == 0) cnt = 0;
  __syncthreads();
  unsigned u = enc16[threadIdx.x * 2];
  int e = (u >> 7) & 0xFF;
  if (e >= 100 && e <= 140) atomicAdd(&cnt, 1);
  __syncthreads();
  if (threadIdx.x == 0) flag[0] = (cnt < 128) ? 1 : 0;
}

// ---------------- batched small-weight conversion ---------------------------
// arena u16 offsets: spk@0(1024) c1@1024(128) c3@1152(128) b1@1280 b2@1536
// b3@1792 b4@2048(256ea) bd1@2304(128) bd2@10624(64) wd3@10688(64)
// bd3@10752(1) wd2T@10880(8192, [o*128+k])
__global__ void cvt_small(const void* spk, const void* c1, const void* c3,
                          const void* b1, const void* b2, const void* b3,
                          const void* b4, const void* bd1, const void* wd2,
                          const void* bd2, const void* wd3, const void* bd3,
                          u16* __restrict__ arena, const int* __restrict__ flag)
{
  int f = *flag;
  int i = blockIdx.x * blockDim.x + threadIdx.x;
  if (i < 1024) { arena[i] = rdw(spk, i, f); return; } i -= 1024;
  if (i < 128)  { arena[1024 + i] = rdw(c1, i, f); return; } i -= 128;
  if (i < 128)  { arena[1152 + i] = rdw(c3, i, f); return; } i -= 128;
  if (i < 256)  { arena[1280 + i] = rdw(b1, i, f); return; } i -= 256;
  if (i < 256)  { arena[1536 + i] = rdw(b2, i, f); return; } i -= 256;
  if (i < 256)  { arena[1792 + i] = rdw(b3, i, f); return; } i -= 256;
  if (i < 256)  { arena[2048 + i] = rdw(b4, i, f); return; } i -= 256;
  if (i < 128)  { arena[2304 + i] = rdw(bd1, i, f); return; } i -= 128;
  if (i < 64)   { arena[10624 + i] = rdw(bd2, i, f); return; } i -= 64;
  if (i < 64)   { arena[10688 + i] = rdw(wd3, i, f); return; } i -= 64;
  if (i < 1)    { arena[10752 + i] = rdw(bd3, i, f); return; } i -= 1;
  if (i < 8192) { int o = i >> 7, k = i & 127;          // wd2T[o,k] = wd2[k,o]
    arena[10880 + i] = rdw(wd2, k * 64 + o, f); }
}

// ---------------- vectorized convert (n multiple of 4) ----------------------
__global__ void cvt4(const void* __restrict__ in, u16* __restrict__ out, int n,
                     const int* __restrict__ flag){
  int i = (blockIdx.x * blockDim.x + threadIdx.x) * 4;
  if (i >= n) return;
  ushort4 o;
  if (*flag) {
    float4 v = *(const float4*)((const float*)in + i);
    o.x = f2b(v.x); o.y = f2b(v.y); o.z = f2b(v.z); o.w = f2b(v.w);
  } else {
    o = *(const ushort4*)((const u16*)in + i);
  }
  *(ushort4*)(out + i) = o;
}

// ---------------- weight packing: transpose B matrices to [NOUT, K] ----------
__global__ void pack_weights(const void* __restrict__ bases1, const void* __restrict__ root1,
                             const void* __restrict__ w2_rel, const void* __restrict__ w2_root,
                             const void* __restrict__ bases3, const void* __restrict__ root3,
                             const void* __restrict__ w4_rel, const void* __restrict__ w4_root,
                             const void* __restrict__ wd1,
                             u16* __restrict__ B1t, u16* __restrict__ B3t,
                             u16* __restrict__ B2t, u16* __restrict__ B4t,
                             u16* __restrict__ D1t, const int* __restrict__ flag)
{
  int f = *flag;
  int idx = blockIdx.x * blockDim.x + threadIdx.x;
  if (idx < 256*2304) { int o = idx / 2304, k = idx % 2304;
    B1t[idx] = (k < 2048) ? rdw(bases1, k*256 + o, f) : rdw(root1, (k-2048)*256 + o, f); return; }
  idx -= 256*2304;
  if (idx < 256*2304) { int o = idx / 2304, k = idx % 2304;
    B3t[idx] = (k < 2048) ? rdw(bases3, k*256 + o, f) : rdw(root3, (k-2048)*256 + o, f); return; }
  idx -= 256*2304;
  if (idx < 256*512) { int o = idx / 512, k = idx % 512;
    B2t[idx] = (k < 256) ? rdw(w2_rel, k*256 + o, f) : rdw(w2_root, (k-256)*256 + o, f); return; }
  idx -= 256*512;
  if (idx < 256*512) { int o = idx / 512, k = idx % 512;
    B4t[idx] = (k < 256) ? rdw(w4_rel, k*256 + o, f) : rdw(w4_root, (k-256)*256 + o, f); return; }
  idx -= 256*512;
  if (idx < 128*768) { int o = idx / 768, k = idx % 768;
    D1t[idx] = rdw(wd1, k*128 + o, f); }
}

// ---------------- x = encoding + spk_table[speaker] -------------------------
__global__ void build_x(const void* __restrict__ enc, const int* __restrict__ speaker,
                        const u16* __restrict__ spkA /* bf16 [4,256] */,
                        u16* __restrict__ X /* [N,256] */, int N,
                        const int* __restrict__ flag)
{
  int f = *flag;
  int idx = blockIdx.x * blockDim.x + threadIdx.x;
  if (idx >= N * 64) return;
  int n = idx >> 6, c = (idx & 63) * 4;
  int sp = speaker[n];
  ushort4 sv = *(const ushort4*)(spkA + (size_t)sp*256 + c);
  float e0, e1, e2, e3;
  if (f) {
    float4 ev = *(const float4*)((const float*)enc + (size_t)n*256 + c);
    e0 = ev.x; e1 = ev.y; e2 = ev.z; e3 = ev.w;
  } else {
    ushort4 ev = *(const ushort4*)((const u16*)enc + (size_t)n*256 + c);
    e0 = b2f(ev.x); e1 = b2f(ev.y); e2 = b2f(ev.z); e3 = b2f(ev.w);
  }
  ushort4 xv;
  xv.x = f2b(e0 + b2f(sv.x));
  xv.y = f2b(e1 + b2f(sv.y));
  xv.z = f2b(e2 + b2f(sv.z));
  xv.w = f2b(e3 + b2f(sv.w));
  *(ushort4*)(X + (size_t)n*256 + c) = xv;
}

// ---------------- dst-degree histogram (only cnt_dst now) -------------------
__global__ void edge_hist(const int* __restrict__ ei, int* cnt_dst, int E)
{
  int e = blockIdx.x * blockDim.x + threadIdx.x;
  if (e >= E) return;
  atomicAdd(&cnt_dst[ei[E + e]], 1);
}

// ---------------- 3-phase parallel exclusive scan ---------------------------
__global__ void scan_p1(const int* __restrict__ cnt, int* __restrict__ partial,
                        int* __restrict__ bsum, int N)
{
  __shared__ int s[256];
  int t = threadIdx.x;
  int g = blockIdx.x * 256 + t;
  int v = (g < N) ? cnt[g] : 0;
  s[t] = v; __syncthreads();
  #pragma unroll
  for (int off = 1; off < 256; off <<= 1) {
    int u = (t >= off) ? s[t - off] : 0;
    __syncthreads();
    s[t] += u;
    __syncthreads();
  }
  partial[g] = s[t];                       // inclusive
  if (t == 255) bsum[blockIdx.x] = s[255];
}

__global__ void scan_p2(int* __restrict__ bsum, int nb)
{
  __shared__ int s[1024];
  int t = threadIdx.x;
  int v = (t < nb) ? bsum[t] : 0;
  s[t] = v; __syncthreads();
  #pragma unroll
  for (int off = 1; off < 1024; off <<= 1) {
    int u = (t >= off) ? s[t - off] : 0;
    __syncthreads();
    s[t] += u;
    __syncthreads();
  }
  if (t < nb) bsum[t] = s[t] - v;          // exclusive
  if (t == nb - 1) bsum[nb] = s[t];        // total
}

__global__ void scan_p3(const int* __restrict__ cnt, const int* __restrict__ partial,
                        const int* __restrict__ bsum, int* __restrict__ basep, int N)
{
  int g = blockIdx.x * 256 + threadIdx.x;
  if (g < N) basep[g] = partial[g] - cnt[g] + bsum[blockIdx.x];
  if (g == 0) basep[N] = bsum[(N + 255) / 256];
}

// ---------------- scatter edges into dst-sorted order, packed ---------------
__global__ void edge_scatter(const int* __restrict__ ei, const int* __restrict__ et,
                             const int* __restrict__ est, const int* __restrict__ basep,
                             int* cursor, int* __restrict__ esorted, int E)
{
  int e = blockIdx.x * blockDim.x + threadIdx.x;
  if (e >= E) return;
  int d = ei[E + e];
  int pos = basep[d] + atomicAdd(&cursor[d], 1);
  esorted[pos] = ei[e] | (et[e] << 17) | (est[e] << 21);  // src<2^17, 4+4 bits rels
}

// ------- merged RGCN aggregation (conv1+conv3), in-wave rel counts ----------
// Mix1[nl, b*256+i] = sum_e comp1[et_e,b]*inv1[n,et_e]*x[src_e, i]; same Mix3.
__global__ __launch_bounds__(256) void rgcn_agg2(
    const int* __restrict__ esorted, const int* __restrict__ basep,
    const u16* __restrict__ X /* [N,256] */,
    const u16* __restrict__ comp1 /* bf16 [16,8] */,
    const u16* __restrict__ comp3 /* bf16 [16,8] */,
    u16* __restrict__ Mix1 /* [CR,2048] */,
    u16* __restrict__ Mix3 /* [CR,2048] */,
    int n0, int CR)
{
  __shared__ float sc1[128], sc3[128];
  if (threadIdx.x < 128) sc1[threadIdx.x] = b2f(comp1[threadIdx.x]);
  else sc3[threadIdx.x - 128] = b2f(comp3[threadIdx.x - 128]);
  __syncthreads();
  int nl = blockIdx.x * 4 + (threadIdx.x >> 6);
  if (nl >= CR) return;
  int n = n0 + nl;
  int lane = threadIdx.x & 63;
  int e0 = basep[n], e1 = basep[n + 1];
  // counting pass: lanes 0-15 count et==lane, lanes 16-31 count est==lane-16
  int myrel = lane & 15;
  int cnt = 0;
  for (int e = e0; e < e1; e++) {
    int rec = esorted[e];
    int r1 = (rec >> 17) & 15, r3 = (rec >> 21) & 15;
    if (lane < 16) cnt += (r1 == myrel);
    else if (lane < 32) cnt += (r3 == myrel);
  }
  float invv = 1.0f / (float)(cnt > 1 ? cnt : 1);
  // main pass
  float acc1[8][4] = {}, acc3[8][4] = {};
  for (int e = e0; e < e1; e++) {
    int rec = esorted[e];
    int src = rec & 0x1FFFF;
    int r1 = (rec >> 17) & 15, r3 = (rec >> 21) & 15;
    float iv1 = __shfl(invv, r1);
    float iv3 = __shfl(invv, 16 + r3);
    ushort4 xr = *(const ushort4*)(X + (size_t)src * 256 + lane * 4);
    float x0 = b2f(xr.x), x1 = b2f(xr.y), x2 = b2f(xr.z), x3 = b2f(xr.w);
    const float* c1p = sc1 + r1 * 8;
    const float* c3p = sc3 + r3 * 8;
    #pragma unroll
    for (int b = 0; b < 8; b++) {
      float w1 = c1p[b] * iv1;
      acc1[b][0] += w1 * x0; acc1[b][1] += w1 * x1;
      acc1[b][2] += w1 * x2; acc1[b][3] += w1 * x3;
      float w3 = c3p[b] * iv3;
      acc3[b][0] += w3 * x0; acc3[b][1] += w3 * x1;
      acc3[b][2] += w3 * x2; acc3[b][3] += w3 * x3;
    }
  }
  #pragma unroll
  for (int b = 0; b < 8; b++) {
    ushort4 o1, o3;
    o1.x = f2b(acc1[b][0]); o1.y = f2b(acc1[b][1]);
    o1.z = f2b(acc1[b][2]); o1.w = f2b(acc1[b][3]);
    o3.x = f2b(acc3[b][0]); o3.y = f2b(acc3[b][1]);
    o3.z = f2b(acc3[b][2]); o3.w = f2b(acc3[b][3]);
    *(ushort4*)(Mix1 + (size_t)nl * 2048 + b * 256 + lane * 4) = o1;
    *(ushort4*)(Mix3 + (size_t)nl * 2048 + b * 256 + lane * 4) = o3;
  }
}

// -------- GraphConv sum-aggregation: 16B/lane, 2 edges per wave-iter --------
__global__ __launch_bounds__(256) void gconv_agg(
    const int* __restrict__ esorted, const int* __restrict__ basep,
    const u16* __restrict__ Hin /* [N,256] */,
    u16* __restrict__ Agg /* [N,256] */, int N)
{
  int n = blockIdx.x * 4 + (threadIdx.x >> 6);
  if (n >= N) return;
  int lane = threadIdx.x & 63;
  int half = lane >> 5, l32 = lane & 31;
  float a[8] = {};
  int e0 = basep[n], e1 = basep[n + 1];
  for (int e = e0; e < e1; e += 2) {
    int ee = e + half;
    bool ok = ee < e1;
    int src = esorted[ok ? ee : e] & 0x1FFFF;
    short8 hv = *(const short8*)(Hin + (size_t)src * 256 + l32 * 8);
    if (ok) {
      #pragma unroll
      for (int j = 0; j < 8; j++) a[j] += b2f((u16)hv[j]);
    }
  }
  #pragma unroll
  for (int j = 0; j < 8; j++) a[j] += __shfl_xor(a[j], 32);
  if (half == 0) {
    short8 o;
    #pragma unroll
    for (int j = 0; j < 8; j++) o[j] = (short)f2b(a[j]);
    *(short8*)(Agg + (size_t)n * 256 + l32 * 8) = o;
  }
}

// ------------- multi-source bf16 MFMA GEMM, 128x32 tiles --------------------
// C = [A0|A1|A2] @ Bt^T + bias. Grid: groups of 8*nblk blocks = 8 m x nblk n;
// same-m n-blocks sit 8 apart in blockIdx (same XCD under %8 round-robin) so
// the shared 128-row A slice is L2-reused. Dual-conv: blocks >= nx use the
// d-set (A0d/Btd/biasd/Coutd); A1/A2 shared.
__global__ __launch_bounds__(256) void gemm_ms(
    const u16* __restrict__ A0, int lda0,
    const u16* __restrict__ A1, int lda1,
    const u16* __restrict__ A2, int lda2,
    int c1, int c2,
    const u16* __restrict__ Bt, /* [nout, K] */
    const u16* __restrict__ bias,
    u16* __restrict__ Cout, int ldc,
    int M, int K, int relu, int nout, int nx,
    const u16* __restrict__ A0d, const u16* __restrict__ Btd,
    const u16* __restrict__ biasd, u16* __restrict__ Coutd)
{
  constexpr int BK = 64;
  constexpr int LDR = 72;                 // padded row stride (u16)
  __shared__ u16 As[128 * LDR];
  __shared__ u16 Bs[32 * LDR];
  int bi = blockIdx.x;
  const u16* A0u = A0; const u16* Btu = Bt; const u16* biasu = bias;
  u16* Cu = Cout;
  if (bi >= nx) { bi -= nx; A0u = A0d; Btu = Btd; biasu = biasd; Cu = Coutd; }
  int nblk = nout >> 5;
  int grpw = nblk << 3;                   // 8*nblk
  int g = bi / grpw, r = bi % grpw;
  int gm = g * 8 + (r & 7);
  int bm = gm * 128;
  if (bm >= M) return;                    // uniform per block — safe
  int bn = (r >> 3) * 32;

  int tid = threadIdx.x;
  int wid = tid >> 6, lane = tid & 63;
  f32x4 acc[2][2];
  #pragma unroll
  for (int i = 0; i < 2; i++)
    #pragma unroll
    for (int j = 0; j < 2; j++) acc[i][j] = (f32x4)0.0f;

  int sr = tid >> 3;            // 0..31 staging row within group
  int sc = (tid & 7) * 8;       // 0..56 staging col (u16)
  int lm = lane & 15, quad = lane >> 4;

  for (int k0 = 0; k0 < K; k0 += BK) {
    const u16* srcp; int ldas, kO;   // wave-uniform (k0 uniform)
    if (k0 < c1)      { srcp = A0u; ldas = lda0; kO = k0; }
    else if (k0 < c2) { srcp = A1;  ldas = lda1; kO = k0 - c1; }
    else              { srcp = A2;  ldas = lda2; kO = k0 - c2; }
    short8 va[4], vb;
    #pragma unroll
    for (int gg = 0; gg < 4; gg++) {
      int gr = bm + gg * 32 + sr; gr = gr < M ? gr : M - 1;
      va[gg] = *(const short8*)(srcp + (size_t)gr * ldas + kO + sc);
    }
    { int br = bn + sr; br = br < nout ? br : nout - 1;
      vb = *(const short8*)(Btu + (size_t)br * K + k0 + sc); }
    #pragma unroll
    for (int gg = 0; gg < 4; gg++)
      *(short8*)(As + (gg * 32 + sr) * LDR + sc) = va[gg];
    *(short8*)(Bs + sr * LDR + sc) = vb;
    __syncthreads();
    #pragma unroll
    for (int kk = 0; kk < BK; kk += 32) {
      short8 af[2], bfv[2];
      #pragma unroll
      for (int mi = 0; mi < 2; mi++) {
        int m = wid * 32 + mi * 16 + lm;
        af[mi] = *(const short8*)(As + m * LDR + kk + quad * 8);
      }
      #pragma unroll
      for (int ni = 0; ni < 2; ni++) {
        int nn = ni * 16 + lm;
        bfv[ni] = *(const short8*)(Bs + nn * LDR + kk + quad * 8);
      }
      #pragma unroll
      for (int mi = 0; mi < 2; mi++)
        #pragma unroll
        for (int ni = 0; ni < 2; ni++)
          acc[mi][ni] = __builtin_amdgcn_mfma_f32_16x16x32_bf16(
              af[mi], bfv[ni], acc[mi][ni], 0, 0, 0);
    }
    __syncthreads();
  }
  #pragma unroll
  for (int ni = 0; ni < 2; ni++) {
    int gn = bn + ni * 16 + lm;
    float bv = b2f(biasu[gn]);
    #pragma unroll
    for (int mi = 0; mi < 2; mi++) {
      int rbase = bm + wid * 32 + mi * 16 + quad * 4;
      #pragma unroll
      for (int rr = 0; rr < 4; rr++) {
        int gmr = rbase + rr;
        if (gmr < M) {
          float v = acc[mi][ni][rr] + bv;
          if (relu) v = fmaxf(v, 0.f);
          Cu[(size_t)gmr * ldc + gn] = f2b(v);
        }
      }
    }
  }
}

// ---------------- final dot: out[n] = sum_o h2m[n,o]*wd3[o] + bd3 -----------
__global__ __launch_bounds__(256) void mlp_tail2(
    const u16* __restrict__ h2m, const u16* __restrict__ wd3,
    const u16* __restrict__ bd3, void* __restrict__ outp, int N,
    const int* __restrict__ flag)
{
  int n = blockIdx.x * 4 + (threadIdx.x >> 6);
  if (n >= N) return;
  int lane = threadIdx.x & 63;
  float r = b2f(h2m[(size_t)n * 64 + lane]) * b2f(wd3[lane]);
  #pragma unroll
  for (int off = 32; off > 0; off >>= 1) r += __shfl_xor(r, off, 64);
  if (lane == 0) {
    float v = r + b2f(bd3[0]);
    if (*flag) ((float*)outp)[n] = v;
    else       ((u16*)outp)[n] = f2b(v);
  }
}

__global__ void sentinel(u16* out, int n, float code){
  int i = blockIdx.x * blockDim.x + threadIdx.x;
  if (i < n) out[i] = f2b(code);
}

extern "C" void kernel_launch(void* const* d_in, const int* in_sizes, int n_in,
                              void* d_out, int out_size, void* d_ws, size_t ws_size,
                              hipStream_t stream)
{
  const void* enc     = d_in[0];
  const int* speaker  = (const int*)d_in[1];
  const int* ei       = (const int*)d_in[2];
  const int* et       = (const int*)d_in[3];
  const int* est      = (const int*)d_in[4];
  const void* spk_tab = d_in[5];
  const void* comp1   = d_in[6];
  const void* bases1  = d_in[7];
  const void* root1   = d_in[8];
  const void* b1      = d_in[9];
  const void* w2_rel  = d_in[10];
  const void* b2      = d_in[11];
  const void* w2_root = d_in[12];
  const void* comp3   = d_in[13];
  const void* bases3  = d_in[14];
  const void* root3   = d_in[15];
  const void* b3      = d_in[16];
  const void* w4_rel  = d_in[17];
  const void* b4      = d_in[18];
  const void* w4_root = d_in[19];
  const void* wd1     = d_in[20];
  const void* bd1     = d_in[21];
  const void* wd2     = d_in[22];
  const void* bd2     = d_in[23];
  const void* wd3     = d_in[24];
  const void* bd3     = d_in[25];

  int N = in_sizes[1];     // 60000
  int E = in_sizes[3];     // 480000
  int nb = (N + 255) / 256;

  char* ws = (char*)d_ws;
  size_t off = 0;
  auto alloc = [&](size_t bytes) -> char* {
    char* p = ws + off; off = (off + bytes + 255) & ~(size_t)255; return p;
  };
  u16* X    = (u16*)alloc((size_t)N * 256 * 2);   // x = enc+spk; later bf16 enc
  u16* hA   = (u16*)alloc((size_t)N * 256 * 2);   // conv1 rgcn out
  u16* hA3  = (u16*)alloc((size_t)N * 256 * 2);   // conv3 rgcn out
  u16* hB   = (u16*)alloc((size_t)N * 256 * 2);   // h1 final
  u16* hC   = (u16*)alloc((size_t)N * 256 * 2);   // h2 final
  u16* AggB = (u16*)alloc((size_t)N * 256 * 2);   // gconv agg; aliased below
  u16* h1m  = AggB;                                // [N,128] after AggB dead
  u16* h2m  = AggB + (size_t)N * 128;              // [N,64]
  u16* B1t  = (u16*)alloc((size_t)256 * 2304 * 2);
  u16* B3t  = (u16*)alloc((size_t)256 * 2304 * 2);
  u16* B2t  = (u16*)alloc((size_t)256 * 512 * 2);
  u16* B4t  = (u16*)alloc((size_t)256 * 512 * 2);
  u16* D1t  = (u16*)alloc((size_t)128 * 768 * 2);
  u16* arena = (u16*)alloc((size_t)20480 * 2);
  int* flag    = (int*)alloc(256);
  // contiguous zero-init region: cnt_dst, cursor
  int* cnt_dst = (int*)alloc((size_t)N * 4);
  int* cursor  = (int*)alloc((size_t)N * 4);
  size_t zspan = (size_t)((char*)cursor - (char*)cnt_dst) + (size_t)N * 4;
  int* basep   = (int*)alloc((size_t)(N + 1) * 4);
  int* partial = (int*)alloc((size_t)nb * 256 * 4);
  int* bsum    = (int*)alloc((size_t)2048 * 4);
  int* esorted = (int*)alloc((size_t)E * 4);

  // arena layout (u16 offsets)
  u16* spkA   = arena + 0;
  u16* comp1A = arena + 1024;
  u16* comp3A = arena + 1152;
  u16* b1A    = arena + 1280;
  u16* b2A    = arena + 1536;
  u16* b3A    = arena + 1792;
  u16* b4A    = arena + 2048;
  u16* bd1A   = arena + 2304;
  u16* bd2A   = arena + 10624;
  u16* wd3A   = arena + 10688;
  u16* bd3A   = arena + 10752;
  u16* wd2T   = arena + 10880;   // [64,128]

  // Mix1+Mix3 chunk: 8 KB per row
  size_t rem = (ws_size > off) ? (ws_size - off) : 0;
  long crl = (long)(rem / (4096 * 2));
  int chunk_rows = (int)((crl / 128) * 128);
  int Mpad = ((N + 127) / 128) * 128;
  if (chunk_rows > Mpad) chunk_rows = Mpad;

  if (chunk_rows < 128) {
    float code = 2000.0f + (float)(ws_size >> 20);
    sentinel<<<(out_size + 255) / 256, 256, 0, stream>>>((u16*)d_out, out_size, code);
    return;
  }
  u16* Mix1blk = (u16*)(ws + off);
  u16* Mix3blk = Mix1blk + (size_t)chunk_rows * 2048;

  hipMemsetAsync(cnt_dst, 0, zspan, stream);

  detect_dtype<<<1, 256, 0, stream>>>((const u16*)enc, flag);
  cvt_small<<<75, 256, 0, stream>>>(spk_tab, comp1, comp3, b1, b2, b3, b4,
                                    bd1, wd2, bd2, wd3, bd3, arena, flag);

  int totpack = 256*2304*2 + 256*512*2 + 128*768;
  pack_weights<<<(totpack + 255) / 256, 256, 0, stream>>>(
      bases1, root1, w2_rel, w2_root, bases3, root3, w4_rel, w4_root, wd1,
      B1t, B3t, B2t, B4t, D1t, flag);
  build_x<<<(N * 64 + 255) / 256, 256, 0, stream>>>(enc, speaker, spkA, X, N, flag);
  edge_hist<<<(E + 255) / 256, 256, 0, stream>>>(ei, cnt_dst, E);
  scan_p1<<<nb, 256, 0, stream>>>(cnt_dst, partial, bsum, N);
  scan_p2<<<1, 1024, 0, stream>>>(bsum, nb);
  scan_p3<<<nb, 256, 0, stream>>>(cnt_dst, partial, bsum, basep, N);
  edge_scatter<<<(E + 255) / 256, 256, 0, stream>>>(ei, et, est, basep, cursor, esorted, E);

  int nb4 = (N + 3) / 4;
  const u16* nul = (const u16*)nullptr;
  auto nx_for = [](int M_, int nout_) {
    int mg = (M_ + 127) / 128;
    int grpw = (nout_ / 32) * 8;
    return ((mg + 7) / 8) * grpw;
  };

  // convs: merged aggregation + dual GEMM per chunk
  for (int n0 = 0; n0 < N; n0 += chunk_rows) {
    int CR = (N - n0 < chunk_rows) ? (N - n0) : chunk_rows;
    rgcn_agg2<<<(CR + 3) / 4, 256, 0, stream>>>(esorted, basep, X, comp1A, comp3A,
                                                Mix1blk, Mix3blk, n0, CR);
    int nx = nx_for(CR, 256);
    gemm_ms<<<2 * nx, 256, 0, stream>>>(
        Mix1blk, 2048, X + (size_t)n0 * 256, 256, nul, 0, 2048, 2304,
        B1t, b1A, hA + (size_t)n0 * 256, 256, CR, 2304, 0, 256, nx,
        Mix3blk, B3t, b3A, hA3 + (size_t)n0 * 256);
  }
  // gconv2: agg(h1_rgcn) -> [agg|h] @ [w2_rel;w2_root] -> hB
  int nxN = nx_for(N, 256);
  gconv_agg<<<nb4, 256, 0, stream>>>(esorted, basep, hA, AggB, N);
  gemm_ms<<<nxN, 256, 0, stream>>>(
      AggB, 256, hA, 256, nul, 0, 256, 512,
      B2t, b2A, hB, 256, N, 512, 0, 256, nxN, nul, nul, nul, (u16*)nullptr);
  // gconv4
  gconv_agg<<<nb4, 256, 0, stream>>>(esorted, basep, hA3, AggB, N);
  cvt4<<<(N * 64 + 255) / 256, 256, 0, stream>>>(enc, X, N * 256, flag);  // X dead -> bf16 enc
  gemm_ms<<<nxN, 256, 0, stream>>>(
      AggB, 256, hA3, 256, nul, 0, 256, 512,
      B4t, b4A, hC, 256, N, 512, 0, 256, nxN, nul, nul, nul, (u16*)nullptr);

  // MLP layer 1: [enc|h1|h2] @ wd1 (+bd1, relu) -> h1m [N,128]
  int nx1 = nx_for(N, 128);
  gemm_ms<<<nx1, 256, 0, stream>>>(
      X, 256, hB, 256, hC, 256, 256, 512,
      D1t, bd1A, h1m, 128, N, 768, 1, 128, nx1, nul, nul, nul, (u16*)nullptr);
  // MLP layer 2: h1m @ wd2 (+bd2, relu) -> h2m [N,64]
  int nx2 = nx_for(N, 64);
  gemm_ms<<<nx2, 256, 0, stream>>>(
      h1m, 128, nul, 0, nul, 0, 128, 128,
      wd2T, bd2A, h2m, 64, N, 128, 1, 64, nx2, nul, nul, nul, (u16*)nullptr);
  // MLP layer 3
  mlp_tail2<<<nb4, 256, 0, stream>>>(h2m, wd3A, bd3A, d_out, N, flag);
}